// Round 9
// baseline (570.767 us; speedup 1.0000x reference)
//
#include <hip/hip_runtime.h>
#include <hip/hip_bf16.h>
#include <stdint.h>

typedef unsigned short u16;
typedef __attribute__((ext_vector_type(8))) short short8;
typedef __attribute__((ext_vector_type(8))) __bf16 bf16x8;
typedef __attribute__((ext_vector_type(4))) float f32x4;
typedef __attribute__((ext_vector_type(4))) float fv4;

#define DEV static __device__ __forceinline__

DEV float bf2f(u16 u) { uint32_t i = ((uint32_t)u) << 16; float f; __builtin_memcpy(&f, &i, 4); return f; }
DEV u16 f2bf(float f) {
    uint32_t i; __builtin_memcpy(&i, &f, 4);
    uint32_t r = i + 0x7FFFu + ((i >> 16) & 1u);
    return (u16)(r >> 16);
}
DEV float lo16f(uint32_t u) { uint32_t i = u << 16; float f; __builtin_memcpy(&f, &i, 4); return f; }
DEV float hi16f(uint32_t u) { uint32_t i = u & 0xFFFF0000u; float f; __builtin_memcpy(&f, &i, 4); return f; }
DEV uint32_t pack2(float a, float b) { return (uint32_t)f2bf(a) | ((uint32_t)f2bf(b) << 16); }
DEV float lrelu(float x) { return x >= 0.f ? x : 0.2f * x; }

#define CHK 4096      // edges per partition block
#define BN2SH 10      // 1024 nodes per bucket
#define BN2 1024

// ---------------- x -> bf16 pre-convert (streaming, near-roofline) ----------------
__global__ __launch_bounds__(256) void k_cvt(const float* __restrict__ in, u16* __restrict__ out, int n4) {
    int i = blockIdx.x * 256 + threadIdx.x;
    if (i < n4) {
        fv4 v = __builtin_nontemporal_load((const fv4*)in + i);
        uint64_t o = (uint64_t)f2bf(v.x) | ((uint64_t)f2bf(v.y) << 16)
                   | ((uint64_t)f2bf(v.z) << 32) | ((uint64_t)f2bf(v.w) << 48);
        __builtin_nontemporal_store(o, (uint64_t*)out + i);
    }
}

// ---------------- W pre-transpose: f32 [k][M] -> bf16 [cb][m][k] (MFMA B-fragment layout) ----------------
__global__ __launch_bounds__(256) void k_wt(const float* __restrict__ W, u16* __restrict__ out, int K, int M) {
    int i = blockIdx.x * 256 + threadIdx.x;   // i indexes (cb, m, c=k-octet)
    int nko = K >> 3;
    int total = (M >> 6) * 64 * nko;
    if (i >= total) return;
    int c = i % nko;
    int m = (i / nko) & 63;
    int cb = i / (nko * 64);
    const float* wp = W + (size_t)(c * 8) * M + cb * 64 + m;
    uint64_t w0 = (uint64_t)f2bf(wp[0])
                | ((uint64_t)f2bf(wp[(size_t)M]) << 16)
                | ((uint64_t)f2bf(wp[(size_t)2 * M]) << 32)
                | ((uint64_t)f2bf(wp[(size_t)3 * M]) << 48);
    uint64_t w1 = (uint64_t)f2bf(wp[(size_t)4 * M])
                | ((uint64_t)f2bf(wp[(size_t)5 * M]) << 16)
                | ((uint64_t)f2bf(wp[(size_t)6 * M]) << 32)
                | ((uint64_t)f2bf(wp[(size_t)7 * M]) << 48);
    uint64_t* d = (uint64_t*)out + (size_t)i * 2;
    d[0] = w0; d[1] = w1;
}

// ---------------- CSR build: atomic-free bucket partition ----------------
__global__ __launch_bounds__(256) void k_hist(const int* __restrict__ dst, int* __restrict__ hist,
                                              int NBUK, int nbp, int E) {
    __shared__ int h[BN2];
    int tid = threadIdx.x;
    for (int i = tid; i < NBUK; i += 256) h[i] = 0;
    __syncthreads();
    int b0 = blockIdx.x * CHK;
    int jend = b0 + CHK < E ? b0 + CHK : E;
    for (int j = b0 + tid; j < jend; j += 256)
        atomicAdd(&h[dst[j] >> BN2SH], 1);
    __syncthreads();
    for (int i = tid; i < NBUK; i += 256) hist[i * nbp + blockIdx.x] = h[i];
}

__global__ void k_scanpart(const int* __restrict__ deg, int* __restrict__ bsum, int n) {
    __shared__ int buf[1024];
    int tid = threadIdx.x;
    int i = blockIdx.x * 1024 + tid;
    int v = (i < n) ? deg[i] : 0;
    buf[tid] = v; __syncthreads();
    for (int d = 512; d > 0; d >>= 1) {
        if (tid < d) buf[tid] += buf[tid + d];
        __syncthreads();
    }
    if (tid == 0) bsum[blockIdx.x] = buf[0];
}

__global__ void k_scanbsum(int* bsum, int nb) {
    if (threadIdx.x == 0) {
        int run = 0;
        for (int b = 0; b < nb; ++b) { int t = bsum[b]; bsum[b] = run; run += t; }
    }
}

__global__ void k_scanonly(const int* __restrict__ in, const int* __restrict__ bsum,
                           int* __restrict__ out, int n) {
    __shared__ int buf[1024];
    int tid = threadIdx.x;
    int i = blockIdx.x * 1024 + tid;
    int v = (i < n) ? in[i] : 0;
    buf[tid] = v; __syncthreads();
    for (int d = 1; d < 1024; d <<= 1) {
        int t = (tid >= d) ? buf[tid - d] : 0;
        __syncthreads();
        buf[tid] += t;
        __syncthreads();
    }
    if (i < n) out[i] = buf[tid] - v + bsum[blockIdx.x];
}

// pass 3: partition edges into bucket-contiguous staging via LDS cursors
// stage entry packed: src (17 bits) | local_dst (10 bits) << 17   [N=100000 < 2^17]
__global__ __launch_bounds__(256) void k_part(const int* __restrict__ src, const int* __restrict__ dst,
                                              const int* __restrict__ scanned, int* __restrict__ stage,
                                              int NBUK, int nbp, int E) {
    __shared__ int cur[BN2];
    int tid = threadIdx.x;
    for (int i = tid; i < NBUK; i += 256) cur[i] = scanned[i * nbp + blockIdx.x];
    __syncthreads();
    int b0 = blockIdx.x * CHK;
    int jend = b0 + CHK < E ? b0 + CHK : E;
    for (int j = b0 + tid; j < jend; j += 256) {
        int d = dst[j];
        int p = atomicAdd(&cur[d >> BN2SH], 1);
        stage[p] = src[j] | ((d & (BN2 - 1)) << 17);
    }
}

// level 2: exact CSR within each bucket (LDS-only atomics, coalesced/local writes)
__global__ __launch_bounds__(256) void k_csr(const int* __restrict__ stage, const int* __restrict__ scanned,
                                             int* __restrict__ off, int* __restrict__ srt,
                                             int NBUK, int nbp, int N, int E) {
    __shared__ int deg[BN2];
    __shared__ int ex[BN2];
    __shared__ int tsum[256];
    int tid = threadIdx.x, b = blockIdx.x;
    int base = b << BN2SH;
    int s0 = scanned[b * nbp];
    int s1 = (b + 1 < NBUK) ? scanned[(b + 1) * nbp] : E;
    for (int i = tid; i < BN2; i += 256) deg[i] = 0;
    __syncthreads();
    for (int j = s0 + tid; j < s1; j += 256) atomicAdd(&deg[(uint32_t)stage[j] >> 17], 1);
    __syncthreads();
    int t4 = tid * 4;
    int d0 = deg[t4], d1 = deg[t4 + 1], d2 = deg[t4 + 2], d3 = deg[t4 + 3];
    int tot = d0 + d1 + d2 + d3;
    tsum[tid] = tot; __syncthreads();
    for (int d = 1; d < 256; d <<= 1) {
        int t = (tid >= d) ? tsum[tid - d] : 0;
        __syncthreads();
        tsum[tid] += t;
        __syncthreads();
    }
    int ebase = tsum[tid] - tot;
    ex[t4] = ebase; ex[t4 + 1] = ebase + d0; ex[t4 + 2] = ebase + d0 + d1; ex[t4 + 3] = ebase + d0 + d1 + d2;
    __syncthreads();
    for (int i = tid; i < BN2; i += 256) { int n = base + i; if (n < N) off[n] = s0 + ex[i]; }
    if (b == 0 && tid == 0) off[N] = E;
    __syncthreads();
    for (int j = s0 + tid; j < s1; j += 256) {
        int sd = stage[j];
        int p = atomicAdd(&ex[(uint32_t)sd >> 17], 1);
        srt[s0 + p] = sd & 0x1FFFF;
    }
}

// ---------------- GEMM: out[N,M](bf16) = concat(A1[N,K1],A2[N,K2])(bf16) @ Wbt (bf16, [cb][m][k]) ----------------
// Fully barrier-free, no LDS: A and B fragments loaded per-lane from global (L1/L2-served).
// Fused attention-coefficient epilogue; hs = log2(C).
__global__ __launch_bounds__(256) void gemm_k(const u16* __restrict__ A1, int K1,
                                              const u16* __restrict__ A2, int K2,
                                              const u16* __restrict__ wbt, int M,
                                              u16* __restrict__ out, int N,
                                              const float* __restrict__ ats, const float* __restrict__ atd,
                                              float* __restrict__ a_src, float* __restrict__ a_dst, int hs) {
    const int K = K1 + K2;
    const int tid = threadIdx.x;
    const int n0 = blockIdx.x * 64;
    const int cb = blockIdx.y * 64;

    const int wv = tid >> 6, lane = tid & 63;
    const int quad = lane >> 4, r = lane & 15;
    f32x4 acc[4];
#pragma unroll
    for (int ct = 0; ct < 4; ++ct) acc[ct] = (f32x4){0.f, 0.f, 0.f, 0.f};

    int arow = n0 + wv * 16 + r;
    int ar = arow < N ? arow : N - 1;
    const u16* rowA1 = A1 + (size_t)ar * K1;
    const u16* rowA2 = A2 ? (A2 + (size_t)ar * K2 - K1) : rowA1;

    const u16* wB = wbt + (size_t)cb * K;   // column-block base (cb is multiple of 64)
    const u16* bp0 = wB + (size_t)(0 * 16 + r) * K + quad * 8;
    const u16* bp1 = wB + (size_t)(1 * 16 + r) * K + quad * 8;
    const u16* bp2 = wB + (size_t)(2 * 16 + r) * K + quad * 8;
    const u16* bp3 = wB + (size_t)(3 * 16 + r) * K + quad * 8;

    const int nit = K >> 5;
    for (int it = 0; it < nit; ++it) {
        int kk = (it << 5) + quad * 8;
        const u16* ap = (kk < K1) ? (rowA1 + kk) : (rowA2 + kk);
        bf16x8 a = __builtin_bit_cast(bf16x8, *(const short8*)ap);
        int ko = it << 5;
        bf16x8 b0 = __builtin_bit_cast(bf16x8, *(const short8*)(bp0 + ko));
        bf16x8 b1 = __builtin_bit_cast(bf16x8, *(const short8*)(bp1 + ko));
        bf16x8 b2 = __builtin_bit_cast(bf16x8, *(const short8*)(bp2 + ko));
        bf16x8 b3 = __builtin_bit_cast(bf16x8, *(const short8*)(bp3 + ko));
        acc[0] = __builtin_amdgcn_mfma_f32_16x16x32_bf16(a, b0, acc[0], 0, 0, 0);
        acc[1] = __builtin_amdgcn_mfma_f32_16x16x32_bf16(a, b1, acc[1], 0, 0, 0);
        acc[2] = __builtin_amdgcn_mfma_f32_16x16x32_bf16(a, b2, acc[2], 0, 0, 0);
        acc[3] = __builtin_amdgcn_mfma_f32_16x16x32_bf16(a, b3, acc[3], 0, 0, 0);
    }

    const int rmask = (1 << hs) - 1;       // 7 or 15: lanes sharing one head
#pragma unroll
    for (int ct = 0; ct < 4; ++ct) {
        int col = cb + ct * 16 + r;
        float as_c = ats[col];
        float ad_c = atd[col];
#pragma unroll
        for (int rg = 0; rg < 4; ++rg) {
            int grow = n0 + wv * 16 + quad * 4 + rg;
            float p = acc[ct][rg];
            if (grow < N) out[(size_t)grow * M + col] = f2bf(p);
            float ps = p * as_c;
            float pd = p * ad_c;
            ps += __shfl_xor(ps, 1); pd += __shfl_xor(pd, 1);
            ps += __shfl_xor(ps, 2); pd += __shfl_xor(pd, 2);
            ps += __shfl_xor(ps, 4); pd += __shfl_xor(pd, 4);
            if (rmask == 15) { ps += __shfl_xor(ps, 8); pd += __shfl_xor(pd, 8); }
            if ((r & rmask) == 0 && grow < N) {
                int head = col >> hs;
                a_src[grow * 8 + head] = ps;
                a_dst[grow * 8 + head] = pd;
            }
        }
    }
}

// ---------------- layer 1/2 aggregation: 2 nodes/wave, 4 channels/lane (dwordx2 gather) ----------------
__global__ __launch_bounds__(256) void agg12(const u16* __restrict__ g,
                                             const float* __restrict__ a_src, const float* __restrict__ a_dst,
                                             const int* __restrict__ off, const int* __restrict__ srt,
                                             const float* __restrict__ bias, const float* __restrict__ pslope,
                                             u16* __restrict__ hout, int N) {
    int tid = threadIdx.x;
    int lane32 = tid & 31;
    int node = blockIdx.x * 8 + (tid >> 5);
    int nd = node < N ? node : N - 1;
    int lane16 = lane32 & 15;     // channel group: ch [lane16*4, +4)
    int sub    = lane32 >> 4;     // edge sub-slot (0..1)
    int hg     = lane16 >> 1;     // head of gather channels (8 ch/head)
    int hw     = lane32 & 7;      // head for weight layout
    int e4     = lane32 >> 3;     // edge slot for weight layout (0..3)
    const char* gb = (const char*)g;

    float ad_acc = a_dst[nd * 8 + hg];
    float ad_w   = a_dst[nd * 8 + hw];
    float ws = __expf(lrelu(a_src[nd * 8 + hg] + ad_acc));
    float m0 = (sub == 0) ? ws : 0.f;        // self-loop counted once
    uint2 gs = *(const uint2*)(gb + ((size_t)nd << 7) + lane16 * 8);
    float s = m0;
    float acc0 = m0 * lo16f(gs.x), acc1 = m0 * hi16f(gs.x);
    float acc2 = m0 * lo16f(gs.y), acc3 = m0 * hi16f(gs.y);

    int jb = off[nd], je = off[nd + 1];
    int addrH = (tid & 32) * 4;               // byte addr of half-wave base lane
    int addrS = addrH + sub * 32;             // srcv bpermute base
    int addrW = addrS + hg * 4;               // weight bpermute base
    int laneoff = lane16 * 8;                 // byte offset within 128B row

    int idx = 0; float asv = 0.f;
    if (jb < je) {
        int jc = jb + e4; jc = jc < je ? jc : je - 1;
        idx = srt[jc];
        asv = a_src[idx * 8 + hw];
    }
    for (int j = jb; j < je; j += 4) {
        float w = __expf(lrelu(asv + ad_w));
        w = (j + e4 < je) ? w : 0.f;          // pre-zero tail weights at source
        int wi = __builtin_bit_cast(int, w);
        int jn = j + 4 + e4; jn = jn < je ? jn : je - 1;
        int idx_n = srt[jn];
        float as_n = a_src[idx_n * 8 + hw];

        int sv0 = __builtin_amdgcn_ds_bpermute(addrS,      idx);
        int wb0 = __builtin_amdgcn_ds_bpermute(addrW,      wi);
        int sv1 = __builtin_amdgcn_ds_bpermute(addrS + 64, idx);
        int wb1 = __builtin_amdgcn_ds_bpermute(addrW + 64, wi);
        uint2 g0 = *(const uint2*)(gb + (((uint32_t)sv0 << 7) + laneoff));
        uint2 g1 = *(const uint2*)(gb + (((uint32_t)sv1 << 7) + laneoff));
        float wv0 = __builtin_bit_cast(float, wb0);
        float wv1 = __builtin_bit_cast(float, wb1);
        s += wv0;
        acc0 += wv0 * lo16f(g0.x); acc1 += wv0 * hi16f(g0.x);
        acc2 += wv0 * lo16f(g0.y); acc3 += wv0 * hi16f(g0.y);
        s += wv1;
        acc0 += wv1 * lo16f(g1.x); acc1 += wv1 * hi16f(g1.x);
        acc2 += wv1 * lo16f(g1.y); acc3 += wv1 * hi16f(g1.y);
        idx = idx_n; asv = as_n;
    }
    // combine the two edge sub-slots (lanes ^16, within each half-wave)
    s    += __shfl_xor(s,    16);
    acc0 += __shfl_xor(acc0, 16); acc1 += __shfl_xor(acc1, 16);
    acc2 += __shfl_xor(acc2, 16); acc3 += __shfl_xor(acc3, 16);
    if (node < N && sub == 0) {
        float r = 1.f / (s + 1e-16f);
        fv4 bv = *(const fv4*)(bias + lane16 * 4);
        float p = pslope[0];
        float v0 = acc0 * r + bv.x; v0 = v0 >= 0.f ? v0 : p * v0;
        float v1 = acc1 * r + bv.y; v1 = v1 >= 0.f ? v1 : p * v1;
        float v2 = acc2 * r + bv.z; v2 = v2 >= 0.f ? v2 : p * v2;
        float v3 = acc3 * r + bv.w; v3 = v3 >= 0.f ? v3 : p * v3;
        uint2 o; o.x = pack2(v0, v1); o.y = pack2(v2, v3);
        *(uint2*)((char*)hout + ((size_t)node << 7) + lane16 * 8) = o;
    }
}

// ---------------- layer 3 aggregation + head-mean + bias + log_softmax ----------------
__global__ __launch_bounds__(256) void agg3(const u16* __restrict__ g,
                                            const float* __restrict__ a_src, const float* __restrict__ a_dst,
                                            const int* __restrict__ off, const int* __restrict__ srt,
                                            const float* __restrict__ b3, float* __restrict__ out, int N) {
    int tid = threadIdx.x;
    int lane = tid & 63;
    int node = blockIdx.x * 4 + (tid >> 6);
    int nd = node < N ? node : N - 1;
    int lane32 = lane & 31;       // ch group: ch [lane32*4, +4)
    int sub = lane >> 5;          // edge sub-slot (0..1)
    int hg = lane32 >> 2;         // head of gather channels (16 ch/head)
    int hw = lane & 7;            // head for weight layout
    int e8 = lane >> 3;           // edge slot for weight layout (0..7)
    const char* gb = (const char*)g;

    float ad_acc = a_dst[nd * 8 + hg];
    float ad_w   = a_dst[nd * 8 + hw];
    float ws = __expf(lrelu(a_src[nd * 8 + hg] + ad_acc));
    float m0 = (sub == 0) ? ws : 0.f;
    uint2 gs = *(const uint2*)(gb + ((size_t)nd << 8) + lane32 * 8);
    float s = m0;
    float acc0 = m0 * lo16f(gs.x), acc1 = m0 * hi16f(gs.x);
    float acc2 = m0 * lo16f(gs.y), acc3 = m0 * hi16f(gs.y);

    int jb = off[nd], je = off[nd + 1];
    int addrS = sub * 32;                 // srcv bpermute base (t adds +64)
    int addrW = addrS + hg * 4;           // weight bpermute base
    int laneoff = lane32 * 8;             // byte offset within 256B row

    int idx = 0; float asv = 0.f;
    if (jb < je) {
        int jc = jb + e8; jc = jc < je ? jc : je - 1;
        idx = srt[jc];
        asv = a_src[idx * 8 + hw];
    }
    for (int j = jb; j < je; j += 8) {
        float w = __expf(lrelu(asv + ad_w));
        w = (j + e8 < je) ? w : 0.f;      // pre-zero tail weights
        int wi = __builtin_bit_cast(int, w);
        int jn = j + 8 + e8; jn = jn < je ? jn : je - 1;
        int idx_n = srt[jn];
        float as_n = a_src[idx_n * 8 + hw];
#pragma unroll
        for (int t = 0; t < 4; ++t) {
            int sv = __builtin_amdgcn_ds_bpermute(addrS + t * 64, idx);
            int wb = __builtin_amdgcn_ds_bpermute(addrW + t * 64, wi);
            uint2 gv = *(const uint2*)(gb + (((uint32_t)sv << 8) + laneoff));
            float wf = __builtin_bit_cast(float, wb);
            s += wf;
            acc0 += wf * lo16f(gv.x); acc1 += wf * hi16f(gv.x);
            acc2 += wf * lo16f(gv.y); acc3 += wf * hi16f(gv.y);
        }
        idx = idx_n; asv = as_n;
    }
    // combine edge sub-slots (lanes ^32)
    s    += __shfl_xor(s,    32);
    acc0 += __shfl_xor(acc0, 32); acc1 += __shfl_xor(acc1, 32);
    acc2 += __shfl_xor(acc2, 32); acc3 += __shfl_xor(acc3, 32);
    // per-head normalize
    float r = 1.f / (s + 1e-16f);
    acc0 *= r; acc1 *= r; acc2 *= r; acc3 *= r;
    // mean over heads: sum lanes stride-4 (xor 4,8,16)
#pragma unroll
    for (int d = 4; d <= 16; d <<= 1) {
        acc0 += __shfl_xor(acc0, d); acc1 += __shfl_xor(acc1, d);
        acc2 += __shfl_xor(acc2, d); acc3 += __shfl_xor(acc3, d);
    }
    // each lane now holds out-ch [(lane32&3)*4, +4) of the 16 outputs
    fv4 bv = *(const fv4*)(b3 + (lane32 & 3) * 4);
    float v0 = acc0 * 0.125f + bv.x;
    float v1 = acc1 * 0.125f + bv.y;
    float v2 = acc2 * 0.125f + bv.z;
    float v3 = acc3 * 0.125f + bv.w;
    float m = fmaxf(fmaxf(v0, v1), fmaxf(v2, v3));
    m = fmaxf(m, __shfl_xor(m, 1)); m = fmaxf(m, __shfl_xor(m, 2));
    float se = __expf(v0 - m) + __expf(v1 - m) + __expf(v2 - m) + __expf(v3 - m);
    se += __shfl_xor(se, 1); se += __shfl_xor(se, 2);
    float lg = __logf(se);
    if (node < N && lane < 4) {
        float4 o;
        o.x = v0 - m - lg; o.y = v1 - m - lg; o.z = v2 - m - lg; o.w = v3 - m - lg;
        *(float4*)(out + (size_t)node * 16 + lane * 4) = o;
    }
}

// ---------------- launch ----------------
extern "C" void kernel_launch(void* const* d_in, const int* in_sizes, int n_in,
                              void* d_out, int out_size, void* d_ws, size_t ws_size,
                              hipStream_t stream) {
    (void)n_in; (void)out_size; (void)ws_size;
    const float* x  = (const float*)d_in[0];
    const int* ei   = (const int*)d_in[1];
    const float* W1 = (const float*)d_in[2];
    const float* as1 = (const float*)d_in[3];
    const float* ad1 = (const float*)d_in[4];
    const float* b1  = (const float*)d_in[5];
    const float* W2  = (const float*)d_in[6];
    const float* as2 = (const float*)d_in[7];
    const float* ad2 = (const float*)d_in[8];
    const float* b2  = (const float*)d_in[9];
    const float* W3  = (const float*)d_in[10];
    const float* as3 = (const float*)d_in[11];
    const float* ad3 = (const float*)d_in[12];
    const float* b3  = (const float*)d_in[13];
    const float* p1  = (const float*)d_in[14];
    const float* p2  = (const float*)d_in[15];
    const int N = in_sizes[0] / 256;
    const int E = in_sizes[1] / 2;
    const int NBUK = (N + BN2 - 1) >> BN2SH;
    const int nbp = (E + CHK - 1) / CHK;
    const int nsc = NBUK * nbp;

    char* ws = (char*)d_ws;
    size_t o = 0;
    auto alloc = [&](size_t bytes) { void* p = ws + o; o = (o + bytes + 255) & ~(size_t)255; return p; };
    int* off     = (int*)alloc((size_t)(N + 1) * 4);
    int* bsum    = (int*)alloc(4096);
    int* hist    = (int*)alloc((size_t)nsc * 4);
    int* scanned = (int*)alloc((size_t)nsc * 4);
    int* srt     = (int*)alloc((size_t)E * 4);
    int* stage   = (int*)alloc((size_t)E * 4);
    u16* xb      = (u16*)alloc((size_t)N * 256 * 2);
    u16* g       = (u16*)alloc((size_t)N * 128 * 2);
    float* a_src = (float*)alloc((size_t)N * 8 * 4);
    float* a_dst = (float*)alloc((size_t)N * 8 * 4);
    u16* h1      = (u16*)alloc((size_t)N * 64 * 2);
    u16* h2      = (u16*)alloc((size_t)N * 64 * 2);
    u16* wb1     = (u16*)alloc((size_t)256 * 64 * 2);
    u16* wb2     = (u16*)alloc((size_t)320 * 64 * 2);
    u16* wb3     = (u16*)alloc((size_t)64 * 128 * 2);

    int n4 = N * 256 / 4;
    k_cvt<<<(n4 + 255) / 256, 256, 0, stream>>>(x, xb, n4);

    // W pre-transpose (tiny)
    k_wt<<<(256 * 64 / 8 + 255) / 256, 256, 0, stream>>>(W1, wb1, 256, 64);
    k_wt<<<(320 * 64 / 8 + 255) / 256, 256, 0, stream>>>(W2, wb2, 320, 64);
    k_wt<<<(64 * 128 / 8 + 255) / 256, 256, 0, stream>>>(W3, wb3, 64, 128);

    // CSR build (atomic-free)
    k_hist<<<nbp, 256, 0, stream>>>(ei + E, hist, NBUK, nbp, E);
    int nS = (nsc + 1023) / 1024;
    k_scanpart<<<nS, 1024, 0, stream>>>(hist, bsum, nsc);
    k_scanbsum<<<1, 64, 0, stream>>>(bsum, nS);
    k_scanonly<<<nS, 1024, 0, stream>>>(hist, bsum, scanned, nsc);
    k_part<<<nbp, 256, 0, stream>>>(ei, ei + E, scanned, stage, NBUK, nbp, E);
    k_csr<<<NBUK, 256, 0, stream>>>(stage, scanned, off, srt, NBUK, nbp, N, E);

    int nb64 = (N + 63) / 64;
    int nb4 = (N + 3) / 4;
    int nb8 = (N + 7) / 8;

    // layer 1: x[N,256] @ W1[256,64]  (+ fused acomp, C=8 -> hs=3)
    gemm_k<<<dim3(nb64, 1), 256, 0, stream>>>(xb, 256, (const u16*)nullptr, 0, wb1, 64, g, N,
                                              as1, ad1, a_src, a_dst, 3);
    agg12<<<nb8, 256, 0, stream>>>(g, a_src, a_dst, off, srt, b1, p1, h1, N);

    // layer 2: concat(x, h1)[N,320] @ W2[320,64]  (+ fused acomp, hs=3)
    gemm_k<<<dim3(nb64, 1), 256, 0, stream>>>(xb, 256, h1, 64, wb2, 64, g, N,
                                              as2, ad2, a_src, a_dst, 3);
    agg12<<<nb8, 256, 0, stream>>>(g, a_src, a_dst, off, srt, b2, p2, h2, N);

    // layer 3: h2[N,64] @ W3[64,128]  (+ fused acomp, C=16 -> hs=4), mean + log_softmax
    gemm_k<<<dim3(nb64, 2), 256, 0, stream>>>(h2, 64, (const u16*)nullptr, 0, wb3, 128, g, N,
                                              as3, ad3, a_src, a_dst, 4);
    agg3<<<nb4, 256, 0, stream>>>(g, a_src, a_dst, off, srt, b3, (float*)d_out, N);
}

// Round 10
// 538.787 us; speedup vs baseline: 1.0594x; 1.0594x over previous
//
#include <hip/hip_runtime.h>
#include <hip/hip_bf16.h>
#include <stdint.h>

typedef unsigned short u16;
typedef __attribute__((ext_vector_type(8))) short short8;
typedef __attribute__((ext_vector_type(8))) __bf16 bf16x8;
typedef __attribute__((ext_vector_type(4))) float f32x4;
typedef __attribute__((ext_vector_type(4))) float fv4;

#define DEV static __device__ __forceinline__

DEV float bf2f(u16 u) { uint32_t i = ((uint32_t)u) << 16; float f; __builtin_memcpy(&f, &i, 4); return f; }
DEV u16 f2bf(float f) {
    uint32_t i; __builtin_memcpy(&i, &f, 4);
    uint32_t r = i + 0x7FFFu + ((i >> 16) & 1u);
    return (u16)(r >> 16);
}
DEV float lo16f(uint32_t u) { uint32_t i = u << 16; float f; __builtin_memcpy(&f, &i, 4); return f; }
DEV float hi16f(uint32_t u) { uint32_t i = u & 0xFFFF0000u; float f; __builtin_memcpy(&f, &i, 4); return f; }
DEV uint32_t pack2(float a, float b) { return (uint32_t)f2bf(a) | ((uint32_t)f2bf(b) << 16); }
DEV float lrelu(float x) { return x >= 0.f ? x : 0.2f * x; }

#define CHK 4096      // edges per partition block
#define BN2SH 10      // 1024 nodes per bucket
#define BN2 1024

// ---------------- x -> bf16 pre-convert (streaming, near-roofline) ----------------
__global__ __launch_bounds__(256) void k_cvt(const float* __restrict__ in, u16* __restrict__ out, int n4) {
    int i = blockIdx.x * 256 + threadIdx.x;
    if (i < n4) {
        fv4 v = __builtin_nontemporal_load((const fv4*)in + i);
        uint64_t o = (uint64_t)f2bf(v.x) | ((uint64_t)f2bf(v.y) << 16)
                   | ((uint64_t)f2bf(v.z) << 32) | ((uint64_t)f2bf(v.w) << 48);
        __builtin_nontemporal_store(o, (uint64_t*)out + i);
    }
}

// ---------------- W pre-transpose: f32 [k][M] -> bf16 [cb][m][k] (MFMA B-fragment layout) ----------------
__global__ __launch_bounds__(256) void k_wt(const float* __restrict__ W, u16* __restrict__ out, int K, int M) {
    int i = blockIdx.x * 256 + threadIdx.x;   // i indexes (cb, m, c=k-octet)
    int nko = K >> 3;
    int total = (M >> 6) * 64 * nko;
    if (i >= total) return;
    int c = i % nko;
    int m = (i / nko) & 63;
    int cb = i / (nko * 64);
    const float* wp = W + (size_t)(c * 8) * M + cb * 64 + m;
    uint64_t w0 = (uint64_t)f2bf(wp[0])
                | ((uint64_t)f2bf(wp[(size_t)M]) << 16)
                | ((uint64_t)f2bf(wp[(size_t)2 * M]) << 32)
                | ((uint64_t)f2bf(wp[(size_t)3 * M]) << 48);
    uint64_t w1 = (uint64_t)f2bf(wp[(size_t)4 * M])
                | ((uint64_t)f2bf(wp[(size_t)5 * M]) << 16)
                | ((uint64_t)f2bf(wp[(size_t)6 * M]) << 32)
                | ((uint64_t)f2bf(wp[(size_t)7 * M]) << 48);
    uint64_t* d = (uint64_t*)out + (size_t)i * 2;
    d[0] = w0; d[1] = w1;
}

// ---------------- CSR build: atomic-free bucket partition ----------------
__global__ __launch_bounds__(256) void k_hist(const int* __restrict__ dst, int* __restrict__ hist,
                                              int NBUK, int nbp, int E) {
    __shared__ int h[BN2];
    int tid = threadIdx.x;
    for (int i = tid; i < NBUK; i += 256) h[i] = 0;
    __syncthreads();
    int b0 = blockIdx.x * CHK;
    int jend = b0 + CHK < E ? b0 + CHK : E;
    for (int j = b0 + tid; j < jend; j += 256)
        atomicAdd(&h[dst[j] >> BN2SH], 1);
    __syncthreads();
    for (int i = tid; i < NBUK; i += 256) hist[i * nbp + blockIdx.x] = h[i];
}

__global__ void k_scanpart(const int* __restrict__ deg, int* __restrict__ bsum, int n) {
    __shared__ int buf[1024];
    int tid = threadIdx.x;
    int i = blockIdx.x * 1024 + tid;
    int v = (i < n) ? deg[i] : 0;
    buf[tid] = v; __syncthreads();
    for (int d = 512; d > 0; d >>= 1) {
        if (tid < d) buf[tid] += buf[tid + d];
        __syncthreads();
    }
    if (tid == 0) bsum[blockIdx.x] = buf[0];
}

__global__ void k_scanbsum(int* bsum, int nb) {
    if (threadIdx.x == 0) {
        int run = 0;
        for (int b = 0; b < nb; ++b) { int t = bsum[b]; bsum[b] = run; run += t; }
    }
}

__global__ void k_scanonly(const int* __restrict__ in, const int* __restrict__ bsum,
                           int* __restrict__ out, int n) {
    __shared__ int buf[1024];
    int tid = threadIdx.x;
    int i = blockIdx.x * 1024 + tid;
    int v = (i < n) ? in[i] : 0;
    buf[tid] = v; __syncthreads();
    for (int d = 1; d < 1024; d <<= 1) {
        int t = (tid >= d) ? buf[tid - d] : 0;
        __syncthreads();
        buf[tid] += t;
        __syncthreads();
    }
    if (i < n) out[i] = buf[tid] - v + bsum[blockIdx.x];
}

// pass 3: partition edges into bucket-contiguous staging via LDS cursors
// stage entry packed: src (17 bits) | local_dst (10 bits) << 17   [N=100000 < 2^17]
__global__ __launch_bounds__(256) void k_part(const int* __restrict__ src, const int* __restrict__ dst,
                                              const int* __restrict__ scanned, int* __restrict__ stage,
                                              int NBUK, int nbp, int E) {
    __shared__ int cur[BN2];
    int tid = threadIdx.x;
    for (int i = tid; i < NBUK; i += 256) cur[i] = scanned[i * nbp + blockIdx.x];
    __syncthreads();
    int b0 = blockIdx.x * CHK;
    int jend = b0 + CHK < E ? b0 + CHK : E;
    for (int j = b0 + tid; j < jend; j += 256) {
        int d = dst[j];
        int p = atomicAdd(&cur[d >> BN2SH], 1);
        stage[p] = src[j] | ((d & (BN2 - 1)) << 17);
    }
}

// level 2: exact CSR within each bucket (LDS-only atomics, coalesced/local writes)
__global__ __launch_bounds__(256) void k_csr(const int* __restrict__ stage, const int* __restrict__ scanned,
                                             int* __restrict__ off, int* __restrict__ srt,
                                             int NBUK, int nbp, int N, int E) {
    __shared__ int deg[BN2];
    __shared__ int ex[BN2];
    __shared__ int tsum[256];
    int tid = threadIdx.x, b = blockIdx.x;
    int base = b << BN2SH;
    int s0 = scanned[b * nbp];
    int s1 = (b + 1 < NBUK) ? scanned[(b + 1) * nbp] : E;
    for (int i = tid; i < BN2; i += 256) deg[i] = 0;
    __syncthreads();
    for (int j = s0 + tid; j < s1; j += 256) atomicAdd(&deg[(uint32_t)stage[j] >> 17], 1);
    __syncthreads();
    int t4 = tid * 4;
    int d0 = deg[t4], d1 = deg[t4 + 1], d2 = deg[t4 + 2], d3 = deg[t4 + 3];
    int tot = d0 + d1 + d2 + d3;
    tsum[tid] = tot; __syncthreads();
    for (int d = 1; d < 256; d <<= 1) {
        int t = (tid >= d) ? tsum[tid - d] : 0;
        __syncthreads();
        tsum[tid] += t;
        __syncthreads();
    }
    int ebase = tsum[tid] - tot;
    ex[t4] = ebase; ex[t4 + 1] = ebase + d0; ex[t4 + 2] = ebase + d0 + d1; ex[t4 + 3] = ebase + d0 + d1 + d2;
    __syncthreads();
    for (int i = tid; i < BN2; i += 256) { int n = base + i; if (n < N) off[n] = s0 + ex[i]; }
    if (b == 0 && tid == 0) off[N] = E;
    __syncthreads();
    for (int j = s0 + tid; j < s1; j += 256) {
        int sd = stage[j];
        int p = atomicAdd(&ex[(uint32_t)sd >> 17], 1);
        srt[s0 + p] = sd & 0x1FFFF;
    }
}

// ---------------- GEMM: out[N,M](bf16) = concat(A1[N,K1],A2[N,K2])(bf16) @ Wbt (bf16, [cb][m][k]) ----------------
// LDS-staged B (vectorized copy from pre-transposed wbt), single barrier, barrier-free MFMA K-loop.
// A-fragments loaded per-lane from global (16B, line-shared across quads, L1-served).
// Fused attention-coefficient epilogue; hs = log2(C).
__global__ __launch_bounds__(256) void gemm_k(const u16* __restrict__ A1, int K1,
                                              const u16* __restrict__ A2, int K2,
                                              const u16* __restrict__ wbt, int M,
                                              u16* __restrict__ out, int N,
                                              const float* __restrict__ ats, const float* __restrict__ atd,
                                              float* __restrict__ a_src, float* __restrict__ a_dst, int hs) {
    __shared__ u16 wt2[40][64][8];          // [k/8][m][k%8], max K=320 -> 40 KB
    const int K = K1 + K2;
    const int nc = K >> 3;
    const int tid = threadIdx.x;
    const int n0 = blockIdx.x * 64;
    const int cb = blockIdx.y * 64;

    const u16* wB = wbt + (size_t)cb * K;   // column-block base: [m][K] rows, m=0..63
    for (int p = tid; p < (nc << 6); p += 256) {
        int c = p >> 6, m = p & 63;         // LDS writes stride-16B across threads: conflict-free
        *(int4*)&wt2[c][m][0] = *(const int4*)(wB + (size_t)m * K + c * 8);
    }
    __syncthreads();

    const int wv = tid >> 6, lane = tid & 63;
    const int quad = lane >> 4, r = lane & 15;
    f32x4 acc[4];
#pragma unroll
    for (int ct = 0; ct < 4; ++ct) acc[ct] = (f32x4){0.f, 0.f, 0.f, 0.f};

    int arow = n0 + wv * 16 + r;
    int ar = arow < N ? arow : N - 1;
    const u16* rowA1 = A1 + (size_t)ar * K1;
    const u16* rowA2 = A2 ? (A2 + (size_t)ar * K2 - K1) : rowA1;

    const int nit = K >> 5;
    for (int it = 0; it < nit; ++it) {
        int kk = (it << 5) + quad * 8;
        const u16* ap = (kk < K1) ? (rowA1 + kk) : (rowA2 + kk);
        bf16x8 a = __builtin_bit_cast(bf16x8, *(const short8*)ap);
        int cbase = it << 2;
#pragma unroll
        for (int ct = 0; ct < 4; ++ct) {
            bf16x8 b = __builtin_bit_cast(bf16x8, *(const short8*)&wt2[cbase + quad][ct * 16 + r][0]);
            acc[ct] = __builtin_amdgcn_mfma_f32_16x16x32_bf16(a, b, acc[ct], 0, 0, 0);
        }
    }

    const int rmask = (1 << hs) - 1;       // 7 or 15: lanes sharing one head
#pragma unroll
    for (int ct = 0; ct < 4; ++ct) {
        int col = cb + ct * 16 + r;
        float as_c = ats[col];
        float ad_c = atd[col];
#pragma unroll
        for (int rg = 0; rg < 4; ++rg) {
            int grow = n0 + wv * 16 + quad * 4 + rg;
            float p = acc[ct][rg];
            if (grow < N) out[(size_t)grow * M + col] = f2bf(p);
            float ps = p * as_c;
            float pd = p * ad_c;
            ps += __shfl_xor(ps, 1); pd += __shfl_xor(pd, 1);
            ps += __shfl_xor(ps, 2); pd += __shfl_xor(pd, 2);
            ps += __shfl_xor(ps, 4); pd += __shfl_xor(pd, 4);
            if (rmask == 15) { ps += __shfl_xor(ps, 8); pd += __shfl_xor(pd, 8); }
            if ((r & rmask) == 0 && grow < N) {
                int head = col >> hs;
                a_src[grow * 8 + head] = ps;
                a_dst[grow * 8 + head] = pd;
            }
        }
    }
}

// ---------------- layer 1/2 aggregation: 2 nodes/wave, 4 channels/lane (dwordx2 gather) ----------------
__global__ __launch_bounds__(256) void agg12(const u16* __restrict__ g,
                                             const float* __restrict__ a_src, const float* __restrict__ a_dst,
                                             const int* __restrict__ off, const int* __restrict__ srt,
                                             const float* __restrict__ bias, const float* __restrict__ pslope,
                                             u16* __restrict__ hout, int N) {
    int tid = threadIdx.x;
    int lane32 = tid & 31;
    int node = blockIdx.x * 8 + (tid >> 5);
    int nd = node < N ? node : N - 1;
    int lane16 = lane32 & 15;     // channel group: ch [lane16*4, +4)
    int sub    = lane32 >> 4;     // edge sub-slot (0..1)
    int hg     = lane16 >> 1;     // head of gather channels (8 ch/head)
    int hw     = lane32 & 7;      // head for weight layout
    int e4     = lane32 >> 3;     // edge slot for weight layout (0..3)
    const char* gb = (const char*)g;

    float ad_acc = a_dst[nd * 8 + hg];
    float ad_w   = a_dst[nd * 8 + hw];
    float ws = __expf(lrelu(a_src[nd * 8 + hg] + ad_acc));
    float m0 = (sub == 0) ? ws : 0.f;        // self-loop counted once
    uint2 gs = *(const uint2*)(gb + ((size_t)nd << 7) + lane16 * 8);
    float s = m0;
    float acc0 = m0 * lo16f(gs.x), acc1 = m0 * hi16f(gs.x);
    float acc2 = m0 * lo16f(gs.y), acc3 = m0 * hi16f(gs.y);

    int jb = off[nd], je = off[nd + 1];
    int addrH = (tid & 32) * 4;               // byte addr of half-wave base lane
    int addrS = addrH + sub * 32;             // srcv bpermute base
    int addrW = addrS + hg * 4;               // weight bpermute base
    int laneoff = lane16 * 8;                 // byte offset within 128B row

    int idx = 0; float asv = 0.f;
    if (jb < je) {
        int jc = jb + e4; jc = jc < je ? jc : je - 1;
        idx = srt[jc];
        asv = a_src[idx * 8 + hw];
    }
    for (int j = jb; j < je; j += 4) {
        float w = __expf(lrelu(asv + ad_w));
        w = (j + e4 < je) ? w : 0.f;          // pre-zero tail weights at source
        int wi = __builtin_bit_cast(int, w);
        int jn = j + 4 + e4; jn = jn < je ? jn : je - 1;
        int idx_n = srt[jn];
        float as_n = a_src[idx_n * 8 + hw];

        int sv0 = __builtin_amdgcn_ds_bpermute(addrS,      idx);
        int wb0 = __builtin_amdgcn_ds_bpermute(addrW,      wi);
        int sv1 = __builtin_amdgcn_ds_bpermute(addrS + 64, idx);
        int wb1 = __builtin_amdgcn_ds_bpermute(addrW + 64, wi);
        uint2 g0 = *(const uint2*)(gb + (((uint32_t)sv0 << 7) + laneoff));
        uint2 g1 = *(const uint2*)(gb + (((uint32_t)sv1 << 7) + laneoff));
        float wv0 = __builtin_bit_cast(float, wb0);
        float wv1 = __builtin_bit_cast(float, wb1);
        s += wv0;
        acc0 += wv0 * lo16f(g0.x); acc1 += wv0 * hi16f(g0.x);
        acc2 += wv0 * lo16f(g0.y); acc3 += wv0 * hi16f(g0.y);
        s += wv1;
        acc0 += wv1 * lo16f(g1.x); acc1 += wv1 * hi16f(g1.x);
        acc2 += wv1 * lo16f(g1.y); acc3 += wv1 * hi16f(g1.y);
        idx = idx_n; asv = as_n;
    }
    // combine the two edge sub-slots (lanes ^16, within each half-wave)
    s    += __shfl_xor(s,    16);
    acc0 += __shfl_xor(acc0, 16); acc1 += __shfl_xor(acc1, 16);
    acc2 += __shfl_xor(acc2, 16); acc3 += __shfl_xor(acc3, 16);
    if (node < N && sub == 0) {
        float r = 1.f / (s + 1e-16f);
        fv4 bv = *(const fv4*)(bias + lane16 * 4);
        float p = pslope[0];
        float v0 = acc0 * r + bv.x; v0 = v0 >= 0.f ? v0 : p * v0;
        float v1 = acc1 * r + bv.y; v1 = v1 >= 0.f ? v1 : p * v1;
        float v2 = acc2 * r + bv.z; v2 = v2 >= 0.f ? v2 : p * v2;
        float v3 = acc3 * r + bv.w; v3 = v3 >= 0.f ? v3 : p * v3;
        uint2 o; o.x = pack2(v0, v1); o.y = pack2(v2, v3);
        *(uint2*)((char*)hout + ((size_t)node << 7) + lane16 * 8) = o;
    }
}

// ---------------- layer 3 aggregation + head-mean + bias + log_softmax ----------------
__global__ __launch_bounds__(256) void agg3(const u16* __restrict__ g,
                                            const float* __restrict__ a_src, const float* __restrict__ a_dst,
                                            const int* __restrict__ off, const int* __restrict__ srt,
                                            const float* __restrict__ b3, float* __restrict__ out, int N) {
    int tid = threadIdx.x;
    int lane = tid & 63;
    int node = blockIdx.x * 4 + (tid >> 6);
    int nd = node < N ? node : N - 1;
    int lane32 = lane & 31;       // ch group: ch [lane32*4, +4)
    int sub = lane >> 5;          // edge sub-slot (0..1)
    int hg = lane32 >> 2;         // head of gather channels (16 ch/head)
    int hw = lane & 7;            // head for weight layout
    int e8 = lane >> 3;           // edge slot for weight layout (0..7)
    const char* gb = (const char*)g;

    float ad_acc = a_dst[nd * 8 + hg];
    float ad_w   = a_dst[nd * 8 + hw];
    float ws = __expf(lrelu(a_src[nd * 8 + hg] + ad_acc));
    float m0 = (sub == 0) ? ws : 0.f;
    uint2 gs = *(const uint2*)(gb + ((size_t)nd << 8) + lane32 * 8);
    float s = m0;
    float acc0 = m0 * lo16f(gs.x), acc1 = m0 * hi16f(gs.x);
    float acc2 = m0 * lo16f(gs.y), acc3 = m0 * hi16f(gs.y);

    int jb = off[nd], je = off[nd + 1];
    int addrS = sub * 32;                 // srcv bpermute base (t adds +64)
    int addrW = addrS + hg * 4;           // weight bpermute base
    int laneoff = lane32 * 8;             // byte offset within 256B row

    int idx = 0; float asv = 0.f;
    if (jb < je) {
        int jc = jb + e8; jc = jc < je ? jc : je - 1;
        idx = srt[jc];
        asv = a_src[idx * 8 + hw];
    }
    for (int j = jb; j < je; j += 8) {
        float w = __expf(lrelu(asv + ad_w));
        w = (j + e8 < je) ? w : 0.f;      // pre-zero tail weights
        int wi = __builtin_bit_cast(int, w);
        int jn = j + 8 + e8; jn = jn < je ? jn : je - 1;
        int idx_n = srt[jn];
        float as_n = a_src[idx_n * 8 + hw];
#pragma unroll
        for (int t = 0; t < 4; ++t) {
            int sv = __builtin_amdgcn_ds_bpermute(addrS + t * 64, idx);
            int wb = __builtin_amdgcn_ds_bpermute(addrW + t * 64, wi);
            uint2 gv = *(const uint2*)(gb + (((uint32_t)sv << 8) + laneoff));
            float wf = __builtin_bit_cast(float, wb);
            s += wf;
            acc0 += wf * lo16f(gv.x); acc1 += wf * hi16f(gv.x);
            acc2 += wf * lo16f(gv.y); acc3 += wf * hi16f(gv.y);
        }
        idx = idx_n; asv = as_n;
    }
    // combine edge sub-slots (lanes ^32)
    s    += __shfl_xor(s,    32);
    acc0 += __shfl_xor(acc0, 32); acc1 += __shfl_xor(acc1, 32);
    acc2 += __shfl_xor(acc2, 32); acc3 += __shfl_xor(acc3, 32);
    // per-head normalize
    float r = 1.f / (s + 1e-16f);
    acc0 *= r; acc1 *= r; acc2 *= r; acc3 *= r;
    // mean over heads: sum lanes stride-4 (xor 4,8,16)
#pragma unroll
    for (int d = 4; d <= 16; d <<= 1) {
        acc0 += __shfl_xor(acc0, d); acc1 += __shfl_xor(acc1, d);
        acc2 += __shfl_xor(acc2, d); acc3 += __shfl_xor(acc3, d);
    }
    // each lane now holds out-ch [(lane32&3)*4, +4) of the 16 outputs
    fv4 bv = *(const fv4*)(b3 + (lane32 & 3) * 4);
    float v0 = acc0 * 0.125f + bv.x;
    float v1 = acc1 * 0.125f + bv.y;
    float v2 = acc2 * 0.125f + bv.z;
    float v3 = acc3 * 0.125f + bv.w;
    float m = fmaxf(fmaxf(v0, v1), fmaxf(v2, v3));
    m = fmaxf(m, __shfl_xor(m, 1)); m = fmaxf(m, __shfl_xor(m, 2));
    float se = __expf(v0 - m) + __expf(v1 - m) + __expf(v2 - m) + __expf(v3 - m);
    se += __shfl_xor(se, 1); se += __shfl_xor(se, 2);
    float lg = __logf(se);
    if (node < N && lane < 4) {
        float4 o;
        o.x = v0 - m - lg; o.y = v1 - m - lg; o.z = v2 - m - lg; o.w = v3 - m - lg;
        *(float4*)(out + (size_t)node * 16 + lane * 4) = o;
    }
}

// ---------------- launch ----------------
extern "C" void kernel_launch(void* const* d_in, const int* in_sizes, int n_in,
                              void* d_out, int out_size, void* d_ws, size_t ws_size,
                              hipStream_t stream) {
    (void)n_in; (void)out_size; (void)ws_size;
    const float* x  = (const float*)d_in[0];
    const int* ei   = (const int*)d_in[1];
    const float* W1 = (const float*)d_in[2];
    const float* as1 = (const float*)d_in[3];
    const float* ad1 = (const float*)d_in[4];
    const float* b1  = (const float*)d_in[5];
    const float* W2  = (const float*)d_in[6];
    const float* as2 = (const float*)d_in[7];
    const float* ad2 = (const float*)d_in[8];
    const float* b2  = (const float*)d_in[9];
    const float* W3  = (const float*)d_in[10];
    const float* as3 = (const float*)d_in[11];
    const float* ad3 = (const float*)d_in[12];
    const float* b3  = (const float*)d_in[13];
    const float* p1  = (const float*)d_in[14];
    const float* p2  = (const float*)d_in[15];
    const int N = in_sizes[0] / 256;
    const int E = in_sizes[1] / 2;
    const int NBUK = (N + BN2 - 1) >> BN2SH;
    const int nbp = (E + CHK - 1) / CHK;
    const int nsc = NBUK * nbp;

    char* ws = (char*)d_ws;
    size_t o = 0;
    auto alloc = [&](size_t bytes) { void* p = ws + o; o = (o + bytes + 255) & ~(size_t)255; return p; };
    int* off     = (int*)alloc((size_t)(N + 1) * 4);
    int* bsum    = (int*)alloc(4096);
    int* hist    = (int*)alloc((size_t)nsc * 4);
    int* scanned = (int*)alloc((size_t)nsc * 4);
    int* srt     = (int*)alloc((size_t)E * 4);
    int* stage   = (int*)alloc((size_t)E * 4);
    u16* xb      = (u16*)alloc((size_t)N * 256 * 2);
    u16* g       = (u16*)alloc((size_t)N * 128 * 2);
    float* a_src = (float*)alloc((size_t)N * 8 * 4);
    float* a_dst = (float*)alloc((size_t)N * 8 * 4);
    u16* h1      = (u16*)alloc((size_t)N * 64 * 2);
    u16* h2      = (u16*)alloc((size_t)N * 64 * 2);
    u16* wb1     = (u16*)alloc((size_t)256 * 64 * 2);
    u16* wb2     = (u16*)alloc((size_t)320 * 64 * 2);
    u16* wb3     = (u16*)alloc((size_t)64 * 128 * 2);

    int n4 = N * 256 / 4;
    k_cvt<<<(n4 + 255) / 256, 256, 0, stream>>>(x, xb, n4);

    // W pre-transpose (tiny)
    k_wt<<<(256 * 64 / 8 + 255) / 256, 256, 0, stream>>>(W1, wb1, 256, 64);
    k_wt<<<(320 * 64 / 8 + 255) / 256, 256, 0, stream>>>(W2, wb2, 320, 64);
    k_wt<<<(64 * 128 / 8 + 255) / 256, 256, 0, stream>>>(W3, wb3, 64, 128);

    // CSR build (atomic-free)
    k_hist<<<nbp, 256, 0, stream>>>(ei + E, hist, NBUK, nbp, E);
    int nS = (nsc + 1023) / 1024;
    k_scanpart<<<nS, 1024, 0, stream>>>(hist, bsum, nsc);
    k_scanbsum<<<1, 64, 0, stream>>>(bsum, nS);
    k_scanonly<<<nS, 1024, 0, stream>>>(hist, bsum, scanned, nsc);
    k_part<<<nbp, 256, 0, stream>>>(ei, ei + E, scanned, stage, NBUK, nbp, E);
    k_csr<<<NBUK, 256, 0, stream>>>(stage, scanned, off, srt, NBUK, nbp, N, E);

    int nb64 = (N + 63) / 64;
    int nb4 = (N + 3) / 4;
    int nb8 = (N + 7) / 8;

    // layer 1: x[N,256] @ W1[256,64]  (+ fused acomp, C=8 -> hs=3)
    gemm_k<<<dim3(nb64, 1), 256, 0, stream>>>(xb, 256, (const u16*)nullptr, 0, wb1, 64, g, N,
                                              as1, ad1, a_src, a_dst, 3);
    agg12<<<nb8, 256, 0, stream>>>(g, a_src, a_dst, off, srt, b1, p1, h1, N);

    // layer 2: concat(x, h1)[N,320] @ W2[320,64]  (+ fused acomp, hs=3)
    gemm_k<<<dim3(nb64, 1), 256, 0, stream>>>(xb, 256, h1, 64, wb2, 64, g, N,
                                              as2, ad2, a_src, a_dst, 3);
    agg12<<<nb8, 256, 0, stream>>>(g, a_src, a_dst, off, srt, b2, p2, h2, N);

    // layer 3: h2[N,64] @ W3[64,128]  (+ fused acomp, C=16 -> hs=4), mean + log_softmax
    gemm_k<<<dim3(nb64, 2), 256, 0, stream>>>(h2, 64, (const u16*)nullptr, 0, wb3, 128, g, N,
                                              as3, ad3, a_src, a_dst, 4);
    agg3<<<nb4, 256, 0, stream>>>(g, a_src, a_dst, off, srt, b3, (float*)d_out, N);
}

// Round 11
// 505.650 us; speedup vs baseline: 1.1288x; 1.0655x over previous
//
#include <hip/hip_runtime.h>
#include <hip/hip_bf16.h>
#include <stdint.h>

typedef unsigned short u16;
typedef __attribute__((ext_vector_type(8))) short short8;
typedef __attribute__((ext_vector_type(8))) __bf16 bf16x8;
typedef __attribute__((ext_vector_type(4))) float f32x4;
typedef __attribute__((ext_vector_type(4))) float fv4;

#define DEV static __device__ __forceinline__

DEV float bf2f(u16 u) { uint32_t i = ((uint32_t)u) << 16; float f; __builtin_memcpy(&f, &i, 4); return f; }
DEV u16 f2bf(float f) {
    uint32_t i; __builtin_memcpy(&i, &f, 4);
    uint32_t r = i + 0x7FFFu + ((i >> 16) & 1u);
    return (u16)(r >> 16);
}
DEV float lo16f(uint32_t u) { uint32_t i = u << 16; float f; __builtin_memcpy(&f, &i, 4); return f; }
DEV float hi16f(uint32_t u) { uint32_t i = u & 0xFFFF0000u; float f; __builtin_memcpy(&f, &i, 4); return f; }
DEV uint32_t pack2(float a, float b) { return (uint32_t)f2bf(a) | ((uint32_t)f2bf(b) << 16); }
DEV float lrelu(float x) { return x >= 0.f ? x : 0.2f * x; }

#define CHK 4096      // edges per partition block
#define BN2SH 10      // 1024 nodes per bucket
#define BN2 1024

// ---------------- W pre-transpose element: f32 [k][M] -> bf16 [cb][m][k] ----------------
DEV void wt_elem(const float* __restrict__ W, u16* __restrict__ out, int K, int M, int i) {
    int nko = K >> 3;
    int total = (M >> 6) * 64 * nko;
    if (i >= total) return;
    int c = i % nko;
    int m = (i / nko) & 63;
    int cb = i / (nko * 64);
    const float* wp = W + (size_t)(c * 8) * M + cb * 64 + m;
    uint64_t w0 = (uint64_t)f2bf(wp[0])
                | ((uint64_t)f2bf(wp[(size_t)M]) << 16)
                | ((uint64_t)f2bf(wp[(size_t)2 * M]) << 32)
                | ((uint64_t)f2bf(wp[(size_t)3 * M]) << 48);
    uint64_t w1 = (uint64_t)f2bf(wp[(size_t)4 * M])
                | ((uint64_t)f2bf(wp[(size_t)5 * M]) << 16)
                | ((uint64_t)f2bf(wp[(size_t)6 * M]) << 32)
                | ((uint64_t)f2bf(wp[(size_t)7 * M]) << 48);
    uint64_t* d = (uint64_t*)out + (size_t)i * 2;
    d[0] = w0; d[1] = w1;
}

// ---------------- prologue: hist (first, feeds scan chain) + W transposes + x->bf16 cvt ----------------
__global__ __launch_bounds__(256) void k_pro(
    const float* __restrict__ x, u16* __restrict__ xb, int n4,
    const float* __restrict__ W1, u16* __restrict__ wb1,
    const float* __restrict__ W2, u16* __restrict__ wb2,
    const float* __restrict__ W3, u16* __restrict__ wb3,
    const int* __restrict__ dst, int* __restrict__ hist,
    int NBUK, int nbp, int E) {
    __shared__ int h[BN2];
    int bid = blockIdx.x;
    int tid = threadIdx.x;
    if (bid < nbp) {
        // histogram role
        for (int i = tid; i < NBUK; i += 256) h[i] = 0;
        __syncthreads();
        int b0 = bid * CHK;
        int jend = b0 + CHK < E ? b0 + CHK : E;
        for (int j = b0 + tid; j < jend; j += 256)
            atomicAdd(&h[dst[j] >> BN2SH], 1);
        __syncthreads();
        for (int i = tid; i < NBUK; i += 256) hist[i * nbp + bid] = h[i];
        return;
    }
    bid -= nbp;
    if (bid < 8)  { wt_elem(W1, wb1, 256, 64, bid * 256 + tid); return; }
    bid -= 8;
    if (bid < 10) { wt_elem(W2, wb2, 320, 64, bid * 256 + tid); return; }
    bid -= 10;
    if (bid < 4)  { wt_elem(W3, wb3, 64, 128, bid * 256 + tid); return; }
    bid -= 4;
    // cvt role
    int i = bid * 256 + tid;
    if (i < n4) {
        fv4 v = __builtin_nontemporal_load((const fv4*)x + i);
        uint64_t o = (uint64_t)f2bf(v.x) | ((uint64_t)f2bf(v.y) << 16)
                   | ((uint64_t)f2bf(v.z) << 32) | ((uint64_t)f2bf(v.w) << 48);
        __builtin_nontemporal_store(o, (uint64_t*)xb + i);
    }
}

// ---------------- scan: per-1024-chunk sums ----------------
__global__ void k_scanpart(const int* __restrict__ deg, int* __restrict__ bsum, int n) {
    __shared__ int buf[1024];
    int tid = threadIdx.x;
    int i = blockIdx.x * 1024 + tid;
    int v = (i < n) ? deg[i] : 0;
    buf[tid] = v; __syncthreads();
    for (int d = 512; d > 0; d >>= 1) {
        if (tid < d) buf[tid] += buf[tid + d];
        __syncthreads();
    }
    if (tid == 0) bsum[blockIdx.x] = buf[0];
}

// scan within chunk; each block computes its own bsum prefix (tiny serial loop on t0)
__global__ void k_scanonly(const int* __restrict__ in, const int* __restrict__ bsum,
                           int* __restrict__ out, int n) {
    __shared__ int buf[1024];
    __shared__ int base;
    int tid = threadIdx.x;
    if (tid == 0) {
        int run = 0;
        for (int b = 0; b < (int)blockIdx.x; ++b) run += bsum[b];
        base = run;
    }
    int i = blockIdx.x * 1024 + tid;
    int v = (i < n) ? in[i] : 0;
    buf[tid] = v; __syncthreads();
    for (int d = 1; d < 1024; d <<= 1) {
        int t = (tid >= d) ? buf[tid - d] : 0;
        __syncthreads();
        buf[tid] += t;
        __syncthreads();
    }
    if (i < n) out[i] = buf[tid] - v + base;
}

// ---------------- GEMM body (templated K; LDS sized exactly) ----------------
template<int TK>
DEV void gemm_body(int bx, int by,
                   const u16* __restrict__ A1, int K1,
                   const u16* __restrict__ A2,
                   const u16* __restrict__ wbt, int M,
                   u16* __restrict__ out, int N,
                   const float* __restrict__ ats, const float* __restrict__ atd,
                   float* __restrict__ a_src, float* __restrict__ a_dst, int hs,
                   u16 (*wt2)[64][8]) {
    const int nc = TK >> 3;
    const int tid = threadIdx.x;
    const int n0 = bx * 64;
    const int cb = by * 64;

    const u16* wB = wbt + (size_t)cb * TK;
    for (int p = tid; p < (nc << 6); p += 256) {
        int c = p >> 6, m = p & 63;         // 16B-stride LDS writes: conflict-free
        *(int4*)&wt2[c][m][0] = *(const int4*)(wB + (size_t)m * TK + c * 8);
    }
    __syncthreads();

    const int wv = tid >> 6, lane = tid & 63;
    const int quad = lane >> 4, r = lane & 15;
    f32x4 acc[4];
#pragma unroll
    for (int ct = 0; ct < 4; ++ct) acc[ct] = (f32x4){0.f, 0.f, 0.f, 0.f};

    int arow = n0 + wv * 16 + r;
    int ar = arow < N ? arow : N - 1;
    const u16* rowA1 = A1 + (size_t)ar * K1;
    const u16* rowA2 = A2 ? (A2 + (size_t)ar * (TK - K1) - K1) : rowA1;

    const int nit = TK >> 5;
#pragma unroll
    for (int it = 0; it < nit; ++it) {
        int kk = (it << 5) + quad * 8;
        const u16* ap = (kk < K1) ? (rowA1 + kk) : (rowA2 + kk);
        bf16x8 a = __builtin_bit_cast(bf16x8, *(const short8*)ap);
        int cbase = it << 2;
#pragma unroll
        for (int ct = 0; ct < 4; ++ct) {
            bf16x8 b = __builtin_bit_cast(bf16x8, *(const short8*)&wt2[cbase + quad][ct * 16 + r][0]);
            acc[ct] = __builtin_amdgcn_mfma_f32_16x16x32_bf16(a, b, acc[ct], 0, 0, 0);
        }
    }

    const int rmask = (1 << hs) - 1;       // 7 or 15: lanes sharing one head
#pragma unroll
    for (int ct = 0; ct < 4; ++ct) {
        int col = cb + ct * 16 + r;
        float as_c = ats[col];
        float ad_c = atd[col];
#pragma unroll
        for (int rg = 0; rg < 4; ++rg) {
            int grow = n0 + wv * 16 + quad * 4 + rg;
            float p = acc[ct][rg];
            if (grow < N) out[(size_t)grow * M + col] = f2bf(p);
            float ps = p * as_c;
            float pd = p * ad_c;
            ps += __shfl_xor(ps, 1); pd += __shfl_xor(pd, 1);
            ps += __shfl_xor(ps, 2); pd += __shfl_xor(pd, 2);
            ps += __shfl_xor(ps, 4); pd += __shfl_xor(pd, 4);
            if (rmask == 15) { ps += __shfl_xor(ps, 8); pd += __shfl_xor(pd, 8); }
            if ((r & rmask) == 0 && grow < N) {
                int head = col >> hs;
                a_src[grow * 8 + head] = ps;
                a_dst[grow * 8 + head] = pd;
            }
        }
    }
}

template<int TK>
__global__ __launch_bounds__(256) void gemm_k(const u16* __restrict__ A1, int K1,
                                              const u16* __restrict__ A2,
                                              const u16* __restrict__ wbt, int M,
                                              u16* __restrict__ out, int N,
                                              const float* __restrict__ ats, const float* __restrict__ atd,
                                              float* __restrict__ a_src, float* __restrict__ a_dst, int hs) {
    __shared__ u16 wt2[TK / 8][64][8];
    gemm_body<TK>(blockIdx.x, blockIdx.y, A1, K1, A2, wbt, M, out, N, ats, atd, a_src, a_dst, hs, wt2);
}

// ---------------- merged: edge partition (bucket staging) + layer-1 GEMM ----------------
__global__ __launch_bounds__(256) void k_pg(
    const int* __restrict__ src, const int* __restrict__ dst,
    const int* __restrict__ scanned, int* __restrict__ stage, int NBUK, int nbp, int E,
    const u16* __restrict__ A1, const u16* __restrict__ wbt,
    u16* __restrict__ out, int N,
    const float* __restrict__ ats, const float* __restrict__ atd,
    float* __restrict__ a_src, float* __restrict__ a_dst) {
    __shared__ u16 wt2[32][64][8];          // 32 KB (K=256); part role aliases first 4 KB
    int bid = blockIdx.x;
    if (bid < nbp) {
        int* cur = (int*)wt2;
        int tid = threadIdx.x;
        for (int i = tid; i < NBUK; i += 256) cur[i] = scanned[i * nbp + bid];
        __syncthreads();
        int b0 = bid * CHK;
        int jend = b0 + CHK < E ? b0 + CHK : E;
        for (int j = b0 + tid; j < jend; j += 256) {
            int d = dst[j];
            int p = atomicAdd(&cur[d >> BN2SH], 1);
            stage[p] = src[j] | ((d & (BN2 - 1)) << 17);
        }
        return;
    }
    gemm_body<256>(bid - nbp, 0, A1, 256, (const u16*)nullptr, wbt, 64, out, N,
                   ats, atd, a_src, a_dst, 3, wt2);
}

// level 2: exact CSR within each bucket (LDS-only atomics, coalesced/local writes)
__global__ __launch_bounds__(256) void k_csr(const int* __restrict__ stage, const int* __restrict__ scanned,
                                             int* __restrict__ off, int* __restrict__ srt,
                                             int NBUK, int nbp, int N, int E) {
    __shared__ int deg[BN2];
    __shared__ int ex[BN2];
    __shared__ int tsum[256];
    int tid = threadIdx.x, b = blockIdx.x;
    int base = b << BN2SH;
    int s0 = scanned[b * nbp];
    int s1 = (b + 1 < NBUK) ? scanned[(b + 1) * nbp] : E;
    for (int i = tid; i < BN2; i += 256) deg[i] = 0;
    __syncthreads();
    for (int j = s0 + tid; j < s1; j += 256) atomicAdd(&deg[(uint32_t)stage[j] >> 17], 1);
    __syncthreads();
    int t4 = tid * 4;
    int d0 = deg[t4], d1 = deg[t4 + 1], d2 = deg[t4 + 2], d3 = deg[t4 + 3];
    int tot = d0 + d1 + d2 + d3;
    tsum[tid] = tot; __syncthreads();
    for (int d = 1; d < 256; d <<= 1) {
        int t = (tid >= d) ? tsum[tid - d] : 0;
        __syncthreads();
        tsum[tid] += t;
        __syncthreads();
    }
    int ebase = tsum[tid] - tot;
    ex[t4] = ebase; ex[t4 + 1] = ebase + d0; ex[t4 + 2] = ebase + d0 + d1; ex[t4 + 3] = ebase + d0 + d1 + d2;
    __syncthreads();
    for (int i = tid; i < BN2; i += 256) { int n = base + i; if (n < N) off[n] = s0 + ex[i]; }
    if (b == 0 && tid == 0) off[N] = E;
    __syncthreads();
    for (int j = s0 + tid; j < s1; j += 256) {
        int sd = stage[j];
        int p = atomicAdd(&ex[(uint32_t)sd >> 17], 1);
        srt[s0 + p] = sd & 0x1FFFF;
    }
}

// ---------------- layer 1/2 aggregation: 2 nodes/wave, 4 channels/lane (dwordx2 gather) ----------------
__global__ __launch_bounds__(256) void agg12(const u16* __restrict__ g,
                                             const float* __restrict__ a_src, const float* __restrict__ a_dst,
                                             const int* __restrict__ off, const int* __restrict__ srt,
                                             const float* __restrict__ bias, const float* __restrict__ pslope,
                                             u16* __restrict__ hout, int N) {
    int tid = threadIdx.x;
    int lane32 = tid & 31;
    int node = blockIdx.x * 8 + (tid >> 5);
    int nd = node < N ? node : N - 1;
    int lane16 = lane32 & 15;     // channel group: ch [lane16*4, +4)
    int sub    = lane32 >> 4;     // edge sub-slot (0..1)
    int hg     = lane16 >> 1;     // head of gather channels (8 ch/head)
    int hw     = lane32 & 7;      // head for weight layout
    int e4     = lane32 >> 3;     // edge slot for weight layout (0..3)
    const char* gb = (const char*)g;

    float ad_acc = a_dst[nd * 8 + hg];
    float ad_w   = a_dst[nd * 8 + hw];
    float ws = __expf(lrelu(a_src[nd * 8 + hg] + ad_acc));
    float m0 = (sub == 0) ? ws : 0.f;        // self-loop counted once
    uint2 gs = *(const uint2*)(gb + ((size_t)nd << 7) + lane16 * 8);
    float s = m0;
    float acc0 = m0 * lo16f(gs.x), acc1 = m0 * hi16f(gs.x);
    float acc2 = m0 * lo16f(gs.y), acc3 = m0 * hi16f(gs.y);

    int jb = off[nd], je = off[nd + 1];
    int addrH = (tid & 32) * 4;               // byte addr of half-wave base lane
    int addrS = addrH + sub * 32;             // srcv bpermute base
    int addrW = addrS + hg * 4;               // weight bpermute base
    int laneoff = lane16 * 8;                 // byte offset within 128B row

    int idx = 0; float asv = 0.f;
    if (jb < je) {
        int jc = jb + e4; jc = jc < je ? jc : je - 1;
        idx = srt[jc];
        asv = a_src[idx * 8 + hw];
    }
    for (int j = jb; j < je; j += 4) {
        float w = __expf(lrelu(asv + ad_w));
        w = (j + e4 < je) ? w : 0.f;          // pre-zero tail weights at source
        int wi = __builtin_bit_cast(int, w);
        int jn = j + 4 + e4; jn = jn < je ? jn : je - 1;
        int idx_n = srt[jn];
        float as_n = a_src[idx_n * 8 + hw];

        int sv0 = __builtin_amdgcn_ds_bpermute(addrS,      idx);
        int wb0 = __builtin_amdgcn_ds_bpermute(addrW,      wi);
        int sv1 = __builtin_amdgcn_ds_bpermute(addrS + 64, idx);
        int wb1 = __builtin_amdgcn_ds_bpermute(addrW + 64, wi);
        uint2 g0 = *(const uint2*)(gb + (((uint32_t)sv0 << 7) + laneoff));
        uint2 g1 = *(const uint2*)(gb + (((uint32_t)sv1 << 7) + laneoff));
        float wv0 = __builtin_bit_cast(float, wb0);
        float wv1 = __builtin_bit_cast(float, wb1);
        s += wv0;
        acc0 += wv0 * lo16f(g0.x); acc1 += wv0 * hi16f(g0.x);
        acc2 += wv0 * lo16f(g0.y); acc3 += wv0 * hi16f(g0.y);
        s += wv1;
        acc0 += wv1 * lo16f(g1.x); acc1 += wv1 * hi16f(g1.x);
        acc2 += wv1 * lo16f(g1.y); acc3 += wv1 * hi16f(g1.y);
        idx = idx_n; asv = as_n;
    }
    // combine the two edge sub-slots (lanes ^16, within each half-wave)
    s    += __shfl_xor(s,    16);
    acc0 += __shfl_xor(acc0, 16); acc1 += __shfl_xor(acc1, 16);
    acc2 += __shfl_xor(acc2, 16); acc3 += __shfl_xor(acc3, 16);
    if (node < N && sub == 0) {
        float r = 1.f / (s + 1e-16f);
        fv4 bv = *(const fv4*)(bias + lane16 * 4);
        float p = pslope[0];
        float v0 = acc0 * r + bv.x; v0 = v0 >= 0.f ? v0 : p * v0;
        float v1 = acc1 * r + bv.y; v1 = v1 >= 0.f ? v1 : p * v1;
        float v2 = acc2 * r + bv.z; v2 = v2 >= 0.f ? v2 : p * v2;
        float v3 = acc3 * r + bv.w; v3 = v3 >= 0.f ? v3 : p * v3;
        uint2 o; o.x = pack2(v0, v1); o.y = pack2(v2, v3);
        *(uint2*)((char*)hout + ((size_t)node << 7) + lane16 * 8) = o;
    }
}

// ---------------- layer 3 aggregation + head-mean + bias + log_softmax ----------------
__global__ __launch_bounds__(256) void agg3(const u16* __restrict__ g,
                                            const float* __restrict__ a_src, const float* __restrict__ a_dst,
                                            const int* __restrict__ off, const int* __restrict__ srt,
                                            const float* __restrict__ b3, float* __restrict__ out, int N) {
    int tid = threadIdx.x;
    int lane = tid & 63;
    int node = blockIdx.x * 4 + (tid >> 6);
    int nd = node < N ? node : N - 1;
    int lane32 = lane & 31;       // ch group: ch [lane32*4, +4)
    int sub = lane >> 5;          // edge sub-slot (0..1)
    int hg = lane32 >> 2;         // head of gather channels (16 ch/head)
    int hw = lane & 7;            // head for weight layout
    int e8 = lane >> 3;           // edge slot for weight layout (0..7)
    const char* gb = (const char*)g;

    float ad_acc = a_dst[nd * 8 + hg];
    float ad_w   = a_dst[nd * 8 + hw];
    float ws = __expf(lrelu(a_src[nd * 8 + hg] + ad_acc));
    float m0 = (sub == 0) ? ws : 0.f;
    uint2 gs = *(const uint2*)(gb + ((size_t)nd << 8) + lane32 * 8);
    float s = m0;
    float acc0 = m0 * lo16f(gs.x), acc1 = m0 * hi16f(gs.x);
    float acc2 = m0 * lo16f(gs.y), acc3 = m0 * hi16f(gs.y);

    int jb = off[nd], je = off[nd + 1];
    int addrS = sub * 32;                 // srcv bpermute base (t adds +64)
    int addrW = addrS + hg * 4;           // weight bpermute base
    int laneoff = lane32 * 8;             // byte offset within 256B row

    int idx = 0; float asv = 0.f;
    if (jb < je) {
        int jc = jb + e8; jc = jc < je ? jc : je - 1;
        idx = srt[jc];
        asv = a_src[idx * 8 + hw];
    }
    for (int j = jb; j < je; j += 8) {
        float w = __expf(lrelu(asv + ad_w));
        w = (j + e8 < je) ? w : 0.f;      // pre-zero tail weights
        int wi = __builtin_bit_cast(int, w);
        int jn = j + 8 + e8; jn = jn < je ? jn : je - 1;
        int idx_n = srt[jn];
        float as_n = a_src[idx_n * 8 + hw];
#pragma unroll
        for (int t = 0; t < 4; ++t) {
            int sv = __builtin_amdgcn_ds_bpermute(addrS + t * 64, idx);
            int wb = __builtin_amdgcn_ds_bpermute(addrW + t * 64, wi);
            uint2 gv = *(const uint2*)(gb + (((uint32_t)sv << 8) + laneoff));
            float wf = __builtin_bit_cast(float, wb);
            s += wf;
            acc0 += wf * lo16f(gv.x); acc1 += wf * hi16f(gv.x);
            acc2 += wf * lo16f(gv.y); acc3 += wf * hi16f(gv.y);
        }
        idx = idx_n; asv = as_n;
    }
    // combine edge sub-slots (lanes ^32)
    s    += __shfl_xor(s,    32);
    acc0 += __shfl_xor(acc0, 32); acc1 += __shfl_xor(acc1, 32);
    acc2 += __shfl_xor(acc2, 32); acc3 += __shfl_xor(acc3, 32);
    // per-head normalize
    float r = 1.f / (s + 1e-16f);
    acc0 *= r; acc1 *= r; acc2 *= r; acc3 *= r;
    // mean over heads: sum lanes stride-4 (xor 4,8,16)
#pragma unroll
    for (int d = 4; d <= 16; d <<= 1) {
        acc0 += __shfl_xor(acc0, d); acc1 += __shfl_xor(acc1, d);
        acc2 += __shfl_xor(acc2, d); acc3 += __shfl_xor(acc3, d);
    }
    // each lane now holds out-ch [(lane32&3)*4, +4) of the 16 outputs
    fv4 bv = *(const fv4*)(b3 + (lane32 & 3) * 4);
    float v0 = acc0 * 0.125f + bv.x;
    float v1 = acc1 * 0.125f + bv.y;
    float v2 = acc2 * 0.125f + bv.z;
    float v3 = acc3 * 0.125f + bv.w;
    float m = fmaxf(fmaxf(v0, v1), fmaxf(v2, v3));
    m = fmaxf(m, __shfl_xor(m, 1)); m = fmaxf(m, __shfl_xor(m, 2));
    float se = __expf(v0 - m) + __expf(v1 - m) + __expf(v2 - m) + __expf(v3 - m);
    se += __shfl_xor(se, 1); se += __shfl_xor(se, 2);
    float lg = __logf(se);
    if (node < N && lane < 4) {
        float4 o;
        o.x = v0 - m - lg; o.y = v1 - m - lg; o.z = v2 - m - lg; o.w = v3 - m - lg;
        *(float4*)(out + (size_t)node * 16 + lane * 4) = o;
    }
}

// ---------------- launch ----------------
extern "C" void kernel_launch(void* const* d_in, const int* in_sizes, int n_in,
                              void* d_out, int out_size, void* d_ws, size_t ws_size,
                              hipStream_t stream) {
    (void)n_in; (void)out_size; (void)ws_size;
    const float* x  = (const float*)d_in[0];
    const int* ei   = (const int*)d_in[1];
    const float* W1 = (const float*)d_in[2];
    const float* as1 = (const float*)d_in[3];
    const float* ad1 = (const float*)d_in[4];
    const float* b1  = (const float*)d_in[5];
    const float* W2  = (const float*)d_in[6];
    const float* as2 = (const float*)d_in[7];
    const float* ad2 = (const float*)d_in[8];
    const float* b2  = (const float*)d_in[9];
    const float* W3  = (const float*)d_in[10];
    const float* as3 = (const float*)d_in[11];
    const float* ad3 = (const float*)d_in[12];
    const float* b3  = (const float*)d_in[13];
    const float* p1  = (const float*)d_in[14];
    const float* p2  = (const float*)d_in[15];
    const int N = in_sizes[0] / 256;
    const int E = in_sizes[1] / 2;
    const int NBUK = (N + BN2 - 1) >> BN2SH;
    const int nbp = (E + CHK - 1) / CHK;
    const int nsc = NBUK * nbp;

    char* ws = (char*)d_ws;
    size_t o = 0;
    auto alloc = [&](size_t bytes) { void* p = ws + o; o = (o + bytes + 255) & ~(size_t)255; return p; };
    int* off     = (int*)alloc((size_t)(N + 1) * 4);
    int* bsum    = (int*)alloc(4096);
    int* hist    = (int*)alloc((size_t)nsc * 4);
    int* scanned = (int*)alloc((size_t)nsc * 4);
    int* srt     = (int*)alloc((size_t)E * 4);
    int* stage   = (int*)alloc((size_t)E * 4);
    u16* xb      = (u16*)alloc((size_t)N * 256 * 2);
    u16* g       = (u16*)alloc((size_t)N * 128 * 2);
    float* a_src = (float*)alloc((size_t)N * 8 * 4);
    float* a_dst = (float*)alloc((size_t)N * 8 * 4);
    u16* h1      = (u16*)alloc((size_t)N * 64 * 2);
    u16* h2      = (u16*)alloc((size_t)N * 64 * 2);
    u16* wb1     = (u16*)alloc((size_t)256 * 64 * 2);
    u16* wb2     = (u16*)alloc((size_t)320 * 64 * 2);
    u16* wb3     = (u16*)alloc((size_t)64 * 128 * 2);

    int n4 = N * 256 / 4;
    int ncvt = (n4 + 255) / 256;

    // prologue: hist + W transposes + cvt, one kernel (roles by blockIdx)
    k_pro<<<nbp + 22 + ncvt, 256, 0, stream>>>(x, xb, n4, W1, wb1, W2, wb2, W3, wb3,
                                               ei + E, hist, NBUK, nbp, E);

    int nS = (nsc + 1023) / 1024;
    k_scanpart<<<nS, 1024, 0, stream>>>(hist, bsum, nsc);
    k_scanonly<<<nS, 1024, 0, stream>>>(hist, bsum, scanned, nsc);

    int nb64 = (N + 63) / 64;
    int nb4 = (N + 3) / 4;
    int nb8 = (N + 7) / 8;

    // merged: edge partition + layer-1 GEMM (+ fused acomp, hs=3)
    k_pg<<<nbp + nb64, 256, 0, stream>>>(ei, ei + E, scanned, stage, NBUK, nbp, E,
                                         xb, wb1, g, N, as1, ad1, a_src, a_dst);
    k_csr<<<NBUK, 256, 0, stream>>>(stage, scanned, off, srt, NBUK, nbp, N, E);

    agg12<<<nb8, 256, 0, stream>>>(g, a_src, a_dst, off, srt, b1, p1, h1, N);

    // layer 2: concat(x, h1)[N,320] @ W2  (+ fused acomp, hs=3)
    gemm_k<320><<<dim3(nb64, 1), 256, 0, stream>>>(xb, 256, h1, wb2, 64, g, N,
                                                   as2, ad2, a_src, a_dst, 3);
    agg12<<<nb8, 256, 0, stream>>>(g, a_src, a_dst, off, srt, b2, p2, h2, N);

    // layer 3: h2[N,64] @ W3  (+ fused acomp, hs=4), mean + log_softmax
    gemm_k<64><<<dim3(nb64, 2), 256, 0, stream>>>(h2, 64, (const u16*)nullptr, wb3, 128, g, N,
                                                  as3, ad3, a_src, a_dst, 4);
    agg3<<<nb4, 256, 0, stream>>>(g, a_src, a_dst, off, srt, b3, (float*)d_out, N);
}

// Round 12
// 483.383 us; speedup vs baseline: 1.1808x; 1.0461x over previous
//
#include <hip/hip_runtime.h>
#include <hip/hip_bf16.h>
#include <stdint.h>

typedef unsigned short u16;
typedef __attribute__((ext_vector_type(8))) short short8;
typedef __attribute__((ext_vector_type(8))) __bf16 bf16x8;
typedef __attribute__((ext_vector_type(4))) float f32x4;
typedef __attribute__((ext_vector_type(4))) float fv4;

#define DEV static __device__ __forceinline__

DEV float bf2f(u16 u) { uint32_t i = ((uint32_t)u) << 16; float f; __builtin_memcpy(&f, &i, 4); return f; }
DEV u16 f2bf(float f) {
    uint32_t i; __builtin_memcpy(&i, &f, 4);
    uint32_t r = i + 0x7FFFu + ((i >> 16) & 1u);
    return (u16)(r >> 16);
}
DEV float lo16f(uint32_t u) { uint32_t i = u << 16; float f; __builtin_memcpy(&f, &i, 4); return f; }
DEV float hi16f(uint32_t u) { uint32_t i = u & 0xFFFF0000u; float f; __builtin_memcpy(&f, &i, 4); return f; }
DEV uint32_t pack2(float a, float b) { return (uint32_t)f2bf(a) | ((uint32_t)f2bf(b) << 16); }
DEV float lrelu(float x) { return x >= 0.f ? x : 0.2f * x; }

#define CHK 4096      // edges per partition block
#define BN2SH 10      // 1024 nodes per bucket
#define BN2 1024

// ---------------- W pre-transpose element: f32 [k][M] -> bf16 [cb][m][k] ----------------
DEV void wt_elem(const float* __restrict__ W, u16* __restrict__ out, int K, int M, int i) {
    int nko = K >> 3;
    int total = (M >> 6) * 64 * nko;
    if (i >= total) return;
    int c = i % nko;
    int m = (i / nko) & 63;
    int cb = i / (nko * 64);
    const float* wp = W + (size_t)(c * 8) * M + cb * 64 + m;
    uint64_t w0 = (uint64_t)f2bf(wp[0])
                | ((uint64_t)f2bf(wp[(size_t)M]) << 16)
                | ((uint64_t)f2bf(wp[(size_t)2 * M]) << 32)
                | ((uint64_t)f2bf(wp[(size_t)3 * M]) << 48);
    uint64_t w1 = (uint64_t)f2bf(wp[(size_t)4 * M])
                | ((uint64_t)f2bf(wp[(size_t)5 * M]) << 16)
                | ((uint64_t)f2bf(wp[(size_t)6 * M]) << 32)
                | ((uint64_t)f2bf(wp[(size_t)7 * M]) << 48);
    uint64_t* d = (uint64_t*)out + (size_t)i * 2;
    d[0] = w0; d[1] = w1;
}

// ---------------- prologue: hist (first, feeds scan chain) + W transposes + x->bf16 cvt ----------------
__global__ __launch_bounds__(256) void k_pro(
    const float* __restrict__ x, u16* __restrict__ xb, int n4,
    const float* __restrict__ W1, u16* __restrict__ wb1,
    const float* __restrict__ W2, u16* __restrict__ wb2,
    const float* __restrict__ W3, u16* __restrict__ wb3,
    const int* __restrict__ dst, int* __restrict__ hist,
    int NBUK, int nbp, int E) {
    __shared__ int h[BN2];
    int bid = blockIdx.x;
    int tid = threadIdx.x;
    if (bid < nbp) {
        for (int i = tid; i < NBUK; i += 256) h[i] = 0;
        __syncthreads();
        int b0 = bid * CHK;
        int jend = b0 + CHK < E ? b0 + CHK : E;
        for (int j = b0 + tid; j < jend; j += 256)
            atomicAdd(&h[dst[j] >> BN2SH], 1);
        __syncthreads();
        for (int i = tid; i < NBUK; i += 256) hist[i * nbp + bid] = h[i];
        return;
    }
    bid -= nbp;
    if (bid < 8)  { wt_elem(W1, wb1, 256, 64, bid * 256 + tid); return; }
    bid -= 8;
    if (bid < 10) { wt_elem(W2, wb2, 320, 64, bid * 256 + tid); return; }
    bid -= 10;
    if (bid < 4)  { wt_elem(W3, wb3, 64, 128, bid * 256 + tid); return; }
    bid -= 4;
    int i = bid * 256 + tid;
    if (i < n4) {
        fv4 v = __builtin_nontemporal_load((const fv4*)x + i);
        uint64_t o = (uint64_t)f2bf(v.x) | ((uint64_t)f2bf(v.y) << 16)
                   | ((uint64_t)f2bf(v.z) << 32) | ((uint64_t)f2bf(v.w) << 48);
        __builtin_nontemporal_store(o, (uint64_t*)xb + i);
    }
}

// ---------------- scan: per-1024-chunk sums ----------------
__global__ void k_scanpart(const int* __restrict__ deg, int* __restrict__ bsum, int n) {
    __shared__ int buf[1024];
    int tid = threadIdx.x;
    int i = blockIdx.x * 1024 + tid;
    int v = (i < n) ? deg[i] : 0;
    buf[tid] = v; __syncthreads();
    for (int d = 512; d > 0; d >>= 1) {
        if (tid < d) buf[tid] += buf[tid + d];
        __syncthreads();
    }
    if (tid == 0) bsum[blockIdx.x] = buf[0];
}

// scan within chunk; each block computes its own bsum prefix (tiny serial loop on t0)
__global__ void k_scanonly(const int* __restrict__ in, const int* __restrict__ bsum,
                           int* __restrict__ out, int n) {
    __shared__ int buf[1024];
    __shared__ int base;
    int tid = threadIdx.x;
    if (tid == 0) {
        int run = 0;
        for (int b = 0; b < (int)blockIdx.x; ++b) run += bsum[b];
        base = run;
    }
    int i = blockIdx.x * 1024 + tid;
    int v = (i < n) ? in[i] : 0;
    buf[tid] = v; __syncthreads();
    for (int d = 1; d < 1024; d <<= 1) {
        int t = (tid >= d) ? buf[tid - d] : 0;
        __syncthreads();
        buf[tid] += t;
        __syncthreads();
    }
    if (i < n) out[i] = buf[tid] - v + base;
}

// ---------------- GEMM body (templated K; LDS reused for epilogue staging) ----------------
// Epilogue: acc -> LDS (bf16, [64][72] padded) -> coalesced dwordx4 C-stores; a_src/a_dst
// computed from the LDS tile with one thread per (row, head) — no cross-lane shuffles.
template<int TK>
DEV void gemm_body(int bx, int by,
                   const u16* __restrict__ A1, int K1,
                   const u16* __restrict__ A2,
                   const u16* __restrict__ wbt, int M,
                   u16* __restrict__ out, int N,
                   const float* __restrict__ ats, const float* __restrict__ atd,
                   float* __restrict__ a_src, float* __restrict__ a_dst, int hs,
                   char* smem) {
    u16 (*wt2)[64][8] = (u16(*)[64][8])smem;
    const int nc = TK >> 3;
    const int tid = threadIdx.x;
    const int n0 = bx * 64;
    const int cb = by * 64;

    const u16* wB = wbt + (size_t)cb * TK;
    for (int p = tid; p < (nc << 6); p += 256) {
        int c = p >> 6, m = p & 63;         // 16B-stride LDS writes: conflict-free
        *(int4*)&wt2[c][m][0] = *(const int4*)(wB + (size_t)m * TK + c * 8);
    }
    __syncthreads();

    const int wv = tid >> 6, lane = tid & 63;
    const int quad = lane >> 4, r = lane & 15;
    f32x4 acc[4];
#pragma unroll
    for (int ct = 0; ct < 4; ++ct) acc[ct] = (f32x4){0.f, 0.f, 0.f, 0.f};

    int arow = n0 + wv * 16 + r;
    int ar = arow < N ? arow : N - 1;
    const u16* rowA1 = A1 + (size_t)ar * K1;
    const u16* rowA2 = A2 ? (A2 + (size_t)ar * (TK - K1) - K1) : rowA1;

    const int nit = TK >> 5;
#pragma unroll
    for (int it = 0; it < nit; ++it) {
        int kk = (it << 5) + quad * 8;
        const u16* ap = (kk < K1) ? (rowA1 + kk) : (rowA2 + kk);
        bf16x8 a = __builtin_bit_cast(bf16x8, *(const short8*)ap);
        int cbase = it << 2;
#pragma unroll
        for (int ct = 0; ct < 4; ++ct) {
            bf16x8 b = __builtin_bit_cast(bf16x8, *(const short8*)&wt2[cbase + quad][ct * 16 + r][0]);
            acc[ct] = __builtin_amdgcn_mfma_f32_16x16x32_bf16(a, b, acc[ct], 0, 0, 0);
        }
    }

    __syncthreads();                         // wt2 dead; reuse LDS for output tile
    u16 (*ob)[72] = (u16(*)[72])smem;        // [64 rows][64 cols + 8 pad]
#pragma unroll
    for (int ct = 0; ct < 4; ++ct)
#pragma unroll
        for (int rg = 0; rg < 4; ++rg)
            ob[wv * 16 + quad * 4 + rg][ct * 16 + r] = f2bf(acc[ct][rg]);
    __syncthreads();

    // coalesced C store: 512 slots = 64 rows x 8 segs of 16B
    for (int p = tid; p < 512; p += 256) {
        int row = p >> 3, seg = p & 7;
        int grow = n0 + row;
        if (grow < N)
            *(int4*)(out + (size_t)grow * M + cb + seg * 8) = *(const int4*)&ob[row][seg * 8];
    }

    // a_src/a_dst: one thread per (row, head-in-block)
    const int hpb = 64 >> hs;               // heads in this 64-col block (8 or 4)
    const int C = 1 << hs;
    for (int p = tid; p < (hpb << 6); p += 256) {
        int row = p >> (6 - hs);
        int hd = p & (hpb - 1);
        int lc = hd << hs;
        int col0 = cb + lc;
        float ps = 0.f, pd = 0.f;
        for (int c = 0; c < C; ++c) {
            float v = bf2f(ob[row][lc + c]);
            ps += v * ats[col0 + c];
            pd += v * atd[col0 + c];
        }
        int grow = n0 + row;
        if (grow < N) {
            a_src[grow * 8 + (col0 >> hs)] = ps;
            a_dst[grow * 8 + (col0 >> hs)] = pd;
        }
    }
}

template<int TK>
__global__ __launch_bounds__(256) void gemm_k(const u16* __restrict__ A1, int K1,
                                              const u16* __restrict__ A2,
                                              const u16* __restrict__ wbt, int M,
                                              u16* __restrict__ out, int N,
                                              const float* __restrict__ ats, const float* __restrict__ atd,
                                              float* __restrict__ a_src, float* __restrict__ a_dst, int hs) {
    constexpr int SB = (TK / 8) * 64 * 16;
    constexpr int SE = 64 * 72 * 2;
    __shared__ char buf[SB > SE ? SB : SE];
    gemm_body<TK>(blockIdx.x, blockIdx.y, A1, K1, A2, wbt, M, out, N, ats, atd, a_src, a_dst, hs, buf);
}

// ---------------- merged: edge partition (bucket staging) + layer-1 GEMM ----------------
__global__ __launch_bounds__(256) void k_pg(
    const int* __restrict__ src, const int* __restrict__ dst,
    const int* __restrict__ scanned, int* __restrict__ stage, int NBUK, int nbp, int E,
    const u16* __restrict__ A1, const u16* __restrict__ wbt,
    u16* __restrict__ out, int N,
    const float* __restrict__ ats, const float* __restrict__ atd,
    float* __restrict__ a_src, float* __restrict__ a_dst) {
    __shared__ char buf[32768];             // K=256 staging (32 KB) >= epilogue 9216B
    int bid = blockIdx.x;
    if (bid < nbp) {
        int* cur = (int*)buf;
        int tid = threadIdx.x;
        for (int i = tid; i < NBUK; i += 256) cur[i] = scanned[i * nbp + bid];
        __syncthreads();
        int b0 = bid * CHK;
        int jend = b0 + CHK < E ? b0 + CHK : E;
        for (int j = b0 + tid; j < jend; j += 256) {
            int d = dst[j];
            int p = atomicAdd(&cur[d >> BN2SH], 1);
            stage[p] = src[j] | ((d & (BN2 - 1)) << 17);
        }
        return;
    }
    gemm_body<256>(bid - nbp, 0, A1, 256, (const u16*)nullptr, wbt, 64, out, N,
                   ats, atd, a_src, a_dst, 3, buf);
}

// level 2: exact CSR within each bucket (LDS-only atomics, coalesced/local writes)
__global__ __launch_bounds__(256) void k_csr(const int* __restrict__ stage, const int* __restrict__ scanned,
                                             int* __restrict__ off, int* __restrict__ srt,
                                             int NBUK, int nbp, int N, int E) {
    __shared__ int deg[BN2];
    __shared__ int ex[BN2];
    __shared__ int tsum[256];
    int tid = threadIdx.x, b = blockIdx.x;
    int base = b << BN2SH;
    int s0 = scanned[b * nbp];
    int s1 = (b + 1 < NBUK) ? scanned[(b + 1) * nbp] : E;
    for (int i = tid; i < BN2; i += 256) deg[i] = 0;
    __syncthreads();
    for (int j = s0 + tid; j < s1; j += 256) atomicAdd(&deg[(uint32_t)stage[j] >> 17], 1);
    __syncthreads();
    int t4 = tid * 4;
    int d0 = deg[t4], d1 = deg[t4 + 1], d2 = deg[t4 + 2], d3 = deg[t4 + 3];
    int tot = d0 + d1 + d2 + d3;
    tsum[tid] = tot; __syncthreads();
    for (int d = 1; d < 256; d <<= 1) {
        int t = (tid >= d) ? tsum[tid - d] : 0;
        __syncthreads();
        tsum[tid] += t;
        __syncthreads();
    }
    int ebase = tsum[tid] - tot;
    ex[t4] = ebase; ex[t4 + 1] = ebase + d0; ex[t4 + 2] = ebase + d0 + d1; ex[t4 + 3] = ebase + d0 + d1 + d2;
    __syncthreads();
    for (int i = tid; i < BN2; i += 256) { int n = base + i; if (n < N) off[n] = s0 + ex[i]; }
    if (b == 0 && tid == 0) off[N] = E;
    __syncthreads();
    for (int j = s0 + tid; j < s1; j += 256) {
        int sd = stage[j];
        int p = atomicAdd(&ex[(uint32_t)sd >> 17], 1);
        srt[s0 + p] = sd & 0x1FFFF;
    }
}

// ---------------- layer 1/2 aggregation: 2 nodes/wave, 4 channels/lane (dwordx2 gather) ----------------
__global__ __launch_bounds__(256) void agg12(const u16* __restrict__ g,
                                             const float* __restrict__ a_src, const float* __restrict__ a_dst,
                                             const int* __restrict__ off, const int* __restrict__ srt,
                                             const float* __restrict__ bias, const float* __restrict__ pslope,
                                             u16* __restrict__ hout, int N) {
    int tid = threadIdx.x;
    int lane32 = tid & 31;
    int node = blockIdx.x * 8 + (tid >> 5);
    int nd = node < N ? node : N - 1;
    int lane16 = lane32 & 15;     // channel group: ch [lane16*4, +4)
    int sub    = lane32 >> 4;     // edge sub-slot (0..1)
    int hg     = lane16 >> 1;     // head of gather channels (8 ch/head)
    int hw     = lane32 & 7;      // head for weight layout
    int e4     = lane32 >> 3;     // edge slot for weight layout (0..3)
    const char* gb = (const char*)g;

    float ad_acc = a_dst[nd * 8 + hg];
    float ad_w   = a_dst[nd * 8 + hw];
    float ws = __expf(lrelu(a_src[nd * 8 + hg] + ad_acc));
    float m0 = (sub == 0) ? ws : 0.f;        // self-loop counted once
    uint2 gs = *(const uint2*)(gb + ((size_t)nd << 7) + lane16 * 8);
    float s = m0;
    float acc0 = m0 * lo16f(gs.x), acc1 = m0 * hi16f(gs.x);
    float acc2 = m0 * lo16f(gs.y), acc3 = m0 * hi16f(gs.y);

    int jb = off[nd], je = off[nd + 1];
    int addrH = (tid & 32) * 4;               // byte addr of half-wave base lane
    int addrS = addrH + sub * 32;             // srcv bpermute base
    int addrW = addrS + hg * 4;               // weight bpermute base
    int laneoff = lane16 * 8;                 // byte offset within 128B row

    int idx = 0; float asv = 0.f;
    if (jb < je) {
        int jc = jb + e4; jc = jc < je ? jc : je - 1;
        idx = srt[jc];
        asv = a_src[idx * 8 + hw];
    }
    for (int j = jb; j < je; j += 4) {
        float w = __expf(lrelu(asv + ad_w));
        w = (j + e4 < je) ? w : 0.f;          // pre-zero tail weights at source
        int wi = __builtin_bit_cast(int, w);
        int jn = j + 4 + e4; jn = jn < je ? jn : je - 1;
        int idx_n = srt[jn];
        float as_n = a_src[idx_n * 8 + hw];

        int sv0 = __builtin_amdgcn_ds_bpermute(addrS,      idx);
        int wb0 = __builtin_amdgcn_ds_bpermute(addrW,      wi);
        int sv1 = __builtin_amdgcn_ds_bpermute(addrS + 64, idx);
        int wb1 = __builtin_amdgcn_ds_bpermute(addrW + 64, wi);
        uint2 g0 = *(const uint2*)(gb + (((uint32_t)sv0 << 7) + laneoff));
        uint2 g1 = *(const uint2*)(gb + (((uint32_t)sv1 << 7) + laneoff));
        float wv0 = __builtin_bit_cast(float, wb0);
        float wv1 = __builtin_bit_cast(float, wb1);
        s += wv0;
        acc0 += wv0 * lo16f(g0.x); acc1 += wv0 * hi16f(g0.x);
        acc2 += wv0 * lo16f(g0.y); acc3 += wv0 * hi16f(g0.y);
        s += wv1;
        acc0 += wv1 * lo16f(g1.x); acc1 += wv1 * hi16f(g1.x);
        acc2 += wv1 * lo16f(g1.y); acc3 += wv1 * hi16f(g1.y);
        idx = idx_n; asv = as_n;
    }
    // combine the two edge sub-slots (lanes ^16, within each half-wave)
    s    += __shfl_xor(s,    16);
    acc0 += __shfl_xor(acc0, 16); acc1 += __shfl_xor(acc1, 16);
    acc2 += __shfl_xor(acc2, 16); acc3 += __shfl_xor(acc3, 16);
    if (node < N && sub == 0) {
        float r = 1.f / (s + 1e-16f);
        fv4 bv = *(const fv4*)(bias + lane16 * 4);
        float p = pslope[0];
        float v0 = acc0 * r + bv.x; v0 = v0 >= 0.f ? v0 : p * v0;
        float v1 = acc1 * r + bv.y; v1 = v1 >= 0.f ? v1 : p * v1;
        float v2 = acc2 * r + bv.z; v2 = v2 >= 0.f ? v2 : p * v2;
        float v3 = acc3 * r + bv.w; v3 = v3 >= 0.f ? v3 : p * v3;
        uint2 o; o.x = pack2(v0, v1); o.y = pack2(v2, v3);
        *(uint2*)((char*)hout + ((size_t)node << 7) + lane16 * 8) = o;
    }
}

// ---------------- layer 3 aggregation + head-mean + bias + log_softmax ----------------
__global__ __launch_bounds__(256) void agg3(const u16* __restrict__ g,
                                            const float* __restrict__ a_src, const float* __restrict__ a_dst,
                                            const int* __restrict__ off, const int* __restrict__ srt,
                                            const float* __restrict__ b3, float* __restrict__ out, int N) {
    int tid = threadIdx.x;
    int lane = tid & 63;
    int node = blockIdx.x * 4 + (tid >> 6);
    int nd = node < N ? node : N - 1;
    int lane32 = lane & 31;       // ch group: ch [lane32*4, +4)
    int sub = lane >> 5;          // edge sub-slot (0..1)
    int hg = lane32 >> 2;         // head of gather channels (16 ch/head)
    int hw = lane & 7;            // head for weight layout
    int e8 = lane >> 3;           // edge slot for weight layout (0..7)
    const char* gb = (const char*)g;

    float ad_acc = a_dst[nd * 8 + hg];
    float ad_w   = a_dst[nd * 8 + hw];
    float ws = __expf(lrelu(a_src[nd * 8 + hg] + ad_acc));
    float m0 = (sub == 0) ? ws : 0.f;
    uint2 gs = *(const uint2*)(gb + ((size_t)nd << 8) + lane32 * 8);
    float s = m0;
    float acc0 = m0 * lo16f(gs.x), acc1 = m0 * hi16f(gs.x);
    float acc2 = m0 * lo16f(gs.y), acc3 = m0 * hi16f(gs.y);

    int jb = off[nd], je = off[nd + 1];
    int addrS = sub * 32;                 // srcv bpermute base (t adds +64)
    int addrW = addrS + hg * 4;           // weight bpermute base
    int laneoff = lane32 * 8;             // byte offset within 256B row

    int idx = 0; float asv = 0.f;
    if (jb < je) {
        int jc = jb + e8; jc = jc < je ? jc : je - 1;
        idx = srt[jc];
        asv = a_src[idx * 8 + hw];
    }
    for (int j = jb; j < je; j += 8) {
        float w = __expf(lrelu(asv + ad_w));
        w = (j + e8 < je) ? w : 0.f;      // pre-zero tail weights
        int wi = __builtin_bit_cast(int, w);
        int jn = j + 8 + e8; jn = jn < je ? jn : je - 1;
        int idx_n = srt[jn];
        float as_n = a_src[idx_n * 8 + hw];
#pragma unroll
        for (int t = 0; t < 4; ++t) {
            int sv = __builtin_amdgcn_ds_bpermute(addrS + t * 64, idx);
            int wb = __builtin_amdgcn_ds_bpermute(addrW + t * 64, wi);
            uint2 gv = *(const uint2*)(gb + (((uint32_t)sv << 8) + laneoff));
            float wf = __builtin_bit_cast(float, wb);
            s += wf;
            acc0 += wf * lo16f(gv.x); acc1 += wf * hi16f(gv.x);
            acc2 += wf * lo16f(gv.y); acc3 += wf * hi16f(gv.y);
        }
        idx = idx_n; asv = as_n;
    }
    // combine edge sub-slots (lanes ^32)
    s    += __shfl_xor(s,    32);
    acc0 += __shfl_xor(acc0, 32); acc1 += __shfl_xor(acc1, 32);
    acc2 += __shfl_xor(acc2, 32); acc3 += __shfl_xor(acc3, 32);
    // per-head normalize
    float r = 1.f / (s + 1e-16f);
    acc0 *= r; acc1 *= r; acc2 *= r; acc3 *= r;
    // mean over heads: sum lanes stride-4 (xor 4,8,16)
#pragma unroll
    for (int d = 4; d <= 16; d <<= 1) {
        acc0 += __shfl_xor(acc0, d); acc1 += __shfl_xor(acc1, d);
        acc2 += __shfl_xor(acc2, d); acc3 += __shfl_xor(acc3, d);
    }
    // each lane now holds out-ch [(lane32&3)*4, +4) of the 16 outputs
    fv4 bv = *(const fv4*)(b3 + (lane32 & 3) * 4);
    float v0 = acc0 * 0.125f + bv.x;
    float v1 = acc1 * 0.125f + bv.y;
    float v2 = acc2 * 0.125f + bv.z;
    float v3 = acc3 * 0.125f + bv.w;
    float m = fmaxf(fmaxf(v0, v1), fmaxf(v2, v3));
    m = fmaxf(m, __shfl_xor(m, 1)); m = fmaxf(m, __shfl_xor(m, 2));
    float se = __expf(v0 - m) + __expf(v1 - m) + __expf(v2 - m) + __expf(v3 - m);
    se += __shfl_xor(se, 1); se += __shfl_xor(se, 2);
    float lg = __logf(se);
    if (node < N && lane < 4) {
        float4 o;
        o.x = v0 - m - lg; o.y = v1 - m - lg; o.z = v2 - m - lg; o.w = v3 - m - lg;
        *(float4*)(out + (size_t)node * 16 + lane * 4) = o;
    }
}

// ---------------- launch ----------------
extern "C" void kernel_launch(void* const* d_in, const int* in_sizes, int n_in,
                              void* d_out, int out_size, void* d_ws, size_t ws_size,
                              hipStream_t stream) {
    (void)n_in; (void)out_size; (void)ws_size;
    const float* x  = (const float*)d_in[0];
    const int* ei   = (const int*)d_in[1];
    const float* W1 = (const float*)d_in[2];
    const float* as1 = (const float*)d_in[3];
    const float* ad1 = (const float*)d_in[4];
    const float* b1  = (const float*)d_in[5];
    const float* W2  = (const float*)d_in[6];
    const float* as2 = (const float*)d_in[7];
    const float* ad2 = (const float*)d_in[8];
    const float* b2  = (const float*)d_in[9];
    const float* W3  = (const float*)d_in[10];
    const float* as3 = (const float*)d_in[11];
    const float* ad3 = (const float*)d_in[12];
    const float* b3  = (const float*)d_in[13];
    const float* p1  = (const float*)d_in[14];
    const float* p2  = (const float*)d_in[15];
    const int N = in_sizes[0] / 256;
    const int E = in_sizes[1] / 2;
    const int NBUK = (N + BN2 - 1) >> BN2SH;
    const int nbp = (E + CHK - 1) / CHK;
    const int nsc = NBUK * nbp;

    char* ws = (char*)d_ws;
    size_t o = 0;
    auto alloc = [&](size_t bytes) { void* p = ws + o; o = (o + bytes + 255) & ~(size_t)255; return p; };
    int* off     = (int*)alloc((size_t)(N + 1) * 4);
    int* bsum    = (int*)alloc(4096);
    int* hist    = (int*)alloc((size_t)nsc * 4);
    int* scanned = (int*)alloc((size_t)nsc * 4);
    int* srt     = (int*)alloc((size_t)E * 4);
    int* stage   = (int*)alloc((size_t)E * 4);
    u16* xb      = (u16*)alloc((size_t)N * 256 * 2);
    u16* g       = (u16*)alloc((size_t)N * 128 * 2);
    float* a_src = (float*)alloc((size_t)N * 8 * 4);
    float* a_dst = (float*)alloc((size_t)N * 8 * 4);
    u16* h1      = (u16*)alloc((size_t)N * 64 * 2);
    u16* h2      = (u16*)alloc((size_t)N * 64 * 2);
    u16* wb1     = (u16*)alloc((size_t)256 * 64 * 2);
    u16* wb2     = (u16*)alloc((size_t)320 * 64 * 2);
    u16* wb3     = (u16*)alloc((size_t)64 * 128 * 2);

    int n4 = N * 256 / 4;
    int ncvt = (n4 + 255) / 256;

    // prologue: hist + W transposes + cvt, one kernel (roles by blockIdx)
    k_pro<<<nbp + 22 + ncvt, 256, 0, stream>>>(x, xb, n4, W1, wb1, W2, wb2, W3, wb3,
                                               ei + E, hist, NBUK, nbp, E);

    int nS = (nsc + 1023) / 1024;
    k_scanpart<<<nS, 1024, 0, stream>>>(hist, bsum, nsc);
    k_scanonly<<<nS, 1024, 0, stream>>>(hist, bsum, scanned, nsc);

    int nb64 = (N + 63) / 64;
    int nb4 = (N + 3) / 4;
    int nb8 = (N + 7) / 8;

    // merged: edge partition + layer-1 GEMM (+ fused acomp, hs=3)
    k_pg<<<nbp + nb64, 256, 0, stream>>>(ei, ei + E, scanned, stage, NBUK, nbp, E,
                                         xb, wb1, g, N, as1, ad1, a_src, a_dst);
    k_csr<<<NBUK, 256, 0, stream>>>(stage, scanned, off, srt, NBUK, nbp, N, E);

    agg12<<<nb8, 256, 0, stream>>>(g, a_src, a_dst, off, srt, b1, p1, h1, N);

    // layer 2: concat(x, h1)[N,320] @ W2  (+ fused acomp, hs=3)
    gemm_k<320><<<dim3(nb64, 1), 256, 0, stream>>>(xb, 256, h1, wb2, 64, g, N,
                                                   as2, ad2, a_src, a_dst, 3);
    agg12<<<nb8, 256, 0, stream>>>(g, a_src, a_dst, off, srt, b2, p2, h2, N);

    // layer 3: h2[N,64] @ W3  (+ fused acomp, hs=4), mean + log_softmax
    gemm_k<64><<<dim3(nb64, 2), 256, 0, stream>>>(h2, 64, (const u16*)nullptr, wb3, 128, g, N,
                                                  as3, ad3, a_src, a_dst, 4);
    agg3<<<nb4, 256, 0, stream>>>(g, a_src, a_dst, off, srt, b3, (float*)d_out, N);
}